// Round 3
// baseline (15506.392 us; speedup 1.0000x reference)
//
#include <hip/hip_runtime.h>
#include <math.h>

#define Bc   8
#define Lc   1024
#define CINc 38
#define Dc   512
#define Ec   3
#define Hc   8
#define DHc  64
#define DFFc 2048
#define TRc  409
#define UNc  615

// ---------------- helpers ----------------

__device__ __forceinline__ float pe_val(int pos, int d) {
  int i = d >> 1;
  float div = expf((float)(2 * i) * (-9.210340371976184f / 512.0f)); // -ln(10000)/D
  float ang = (float)pos * div;
  return (d & 1) ? cosf(ang) : sinf(ang);
}

__device__ __forceinline__ float apply_act(float v, int act) {
  if (act == 1) return v > 0.f ? v : 0.f;                       // relu
  if (act == 2) {                                               // gelu (tanh approx, jax default)
    float c = 0.7978845608028654f;
    float t = tanhf(c * (v + 0.044715f * v * v * v));
    return 0.5f * v * (1.0f + t);
  }
  if (act == 3) return 1.0f / (1.0f + expf(-v));                // sigmoid
  return v;
}

// ---------------- embedding: circular conv3 + PE ----------------
// grid (Lc, Bc), block 512
__global__ void embed_kernel(const float* __restrict__ x, const float* __restrict__ w,
                             float* __restrict__ ex) {
  int l = blockIdx.x, b = blockIdx.y, d = threadIdx.x;
  __shared__ float xs[3 * CINc];
  if (d < 3 * CINc) {
    int k = d / CINc, c = d - (d / CINc) * CINc;
    int lsrc = l + k - 1;
    if (lsrc < 0) lsrc += Lc;
    if (lsrc >= Lc) lsrc -= Lc;
    xs[d] = x[((size_t)b * Lc + lsrc) * CINc + c];
  }
  __syncthreads();
  float acc = 0.f;
  #pragma unroll 3
  for (int k = 0; k < 3; ++k)
    for (int c = 0; c < CINc; ++c)
      acc += xs[k * CINc + c] * w[((size_t)(k * CINc + c)) * Dc + d];
  ex[((size_t)b * Lc + l) * Dc + d] = acc + pe_val(l, d);
}

// ---------------- diff: mean_d |ex[l+1]-ex[l]| ----------------
// grid Bc*Lc, block 64 (one wave)
__global__ void diff_kernel(const float* __restrict__ ex, float* __restrict__ diff) {
  int bl = blockIdx.x;
  int l = bl & (Lc - 1);
  int tid = threadIdx.x;
  if (l == Lc - 1) { if (tid == 0) diff[bl] = -1.0f; return; }  // sentinel: score=inf => smallest
  const float* a = ex + (size_t)bl * Dc;
  const float* b = a + Dc;
  float s = 0.f;
  for (int d = tid; d < Dc; d += 64) s += fabsf(b[d] - a[d]);
  #pragma unroll
  for (int off = 32; off > 0; off >>= 1) s += __shfl_down(s, off);
  if (tid == 0) diff[bl] = s * (1.0f / Dc);
}

// ---------------- dual top-k partition by rank ----------------
// grid Bc, block 1024
__global__ void select_kernel(const float* __restrict__ diff, int* __restrict__ mlist,
                              int* __restrict__ ulist) {
  int b = blockIdx.x, l = threadIdx.x;
  __shared__ float ds[Lc];
  __shared__ int flag[Lc];
  ds[l] = diff[(size_t)b * Lc + l];
  __syncthreads();
  float mine = ds[l];
  int rank = 0;
  for (int j = 0; j < Lc; ++j) {
    float o = ds[j];
    rank += (o < mine) || (o == mine && j < l);
  }
  int is_m = (rank < TRc) ? 1 : 0;
  flag[l] = is_m;
  __syncthreads();
  int pre = 0;
  for (int j = 0; j < l; ++j) pre += flag[j];
  if (is_m) mlist[b * TRc + pre] = l;
  else      ulist[b * UNc + (l - pre)] = l;
}

// ---------------- gather unmasked tokens ----------------
// grid (UNc, Bc), block 512
__global__ void gather_kernel(const float* __restrict__ ex, const int* __restrict__ ulist,
                              float* __restrict__ u) {
  int i = blockIdx.x, b = blockIdx.y, d = threadIdx.x;
  int l = ulist[b * UNc + i];
  u[((size_t)b * UNc + i) * Dc + d] = ex[((size_t)b * Lc + l) * Dc + d];
}

// ---------------- scatter ----------------
// grid (UNc, Bc), block 512
__global__ void scatter_unmasked(const float* __restrict__ u, const int* __restrict__ ulist,
                                 float* __restrict__ tokens) {
  int i = blockIdx.x, b = blockIdx.y, d = threadIdx.x;
  int l = ulist[b * UNc + i];
  tokens[((size_t)b * Lc + l) * Dc + d] = u[((size_t)b * UNc + i) * Dc + d];
}
// grid (TRc, Bc), block 512
__global__ void scatter_masked(const float* __restrict__ mtok, const int* __restrict__ mlist,
                               float* __restrict__ tokens) {
  int i = blockIdx.x, b = blockIdx.y, d = threadIdx.x;
  int l = mlist[b * TRc + i];
  tokens[((size_t)b * Lc + l) * Dc + d] = mtok[d] + pe_val(l, d);
}

// ---------------- generic GEMM: C = act(A[MxK] @ W[KxN] + bias) ----------------
// block 256 (16x16 threads, 4x4 per thread => 64x64 tile), K step 16
#define GBM 64
#define GBN 64
#define GBK 16
__global__ __launch_bounds__(256) void gemm_kernel(const float* __restrict__ A,
                                                   const float* __restrict__ W,
                                                   const float* __restrict__ bias,
                                                   float* __restrict__ C,
                                                   int M, int N, int K, int act) {
  __shared__ float As[GBK][GBM + 1];
  __shared__ float Bs[GBK][GBN + 1];
  int tid = threadIdx.x;
  int tx = tid & 15, ty = tid >> 4;
  int rowBase = blockIdx.y * GBM;
  int colBase = blockIdx.x * GBN;
  float acc[4][4] = {{0.f}};
  for (int k0 = 0; k0 < K; k0 += GBK) {
    #pragma unroll
    for (int t = 0; t < 4; ++t) {
      int idx = tid + t * 256;
      int r = idx >> 4, kk = idx & 15;
      int row = rowBase + r;
      As[kk][r] = (row < M) ? A[(size_t)row * K + k0 + kk] : 0.f;
    }
    #pragma unroll
    for (int t = 0; t < 4; ++t) {
      int idx = tid + t * 256;
      int kk = idx >> 6, c = idx & 63;
      Bs[kk][c] = W[(size_t)(k0 + kk) * N + colBase + c];
    }
    __syncthreads();
    #pragma unroll
    for (int kk = 0; kk < GBK; ++kk) {
      float a0 = As[kk][ty * 4 + 0], a1 = As[kk][ty * 4 + 1];
      float a2 = As[kk][ty * 4 + 2], a3 = As[kk][ty * 4 + 3];
      float b0 = Bs[kk][tx * 4 + 0], b1 = Bs[kk][tx * 4 + 1];
      float b2 = Bs[kk][tx * 4 + 2], b3 = Bs[kk][tx * 4 + 3];
      acc[0][0] += a0 * b0; acc[0][1] += a0 * b1; acc[0][2] += a0 * b2; acc[0][3] += a0 * b3;
      acc[1][0] += a1 * b0; acc[1][1] += a1 * b1; acc[1][2] += a1 * b2; acc[1][3] += a1 * b3;
      acc[2][0] += a2 * b0; acc[2][1] += a2 * b1; acc[2][2] += a2 * b2; acc[2][3] += a2 * b3;
      acc[3][0] += a3 * b0; acc[3][1] += a3 * b1; acc[3][2] += a3 * b2; acc[3][3] += a3 * b3;
    }
    __syncthreads();
  }
  #pragma unroll
  for (int i = 0; i < 4; ++i) {
    int row = rowBase + ty * 4 + i;
    if (row >= M) continue;
    #pragma unroll
    for (int j = 0; j < 4; ++j) {
      int col = colBase + tx * 4 + j;
      float v = acc[i][j] + (bias ? bias[col] : 0.f);
      C[(size_t)row * N + col] = apply_act(v, act);
    }
  }
}

// ---------------- attention scores + softmax ----------------
// grid (Lq, Bc*Hc), block 256.  att[b,h,q,k] layout [B,H,Lq,Lq]
__global__ __launch_bounds__(256) void attn_scores_kernel(const float* __restrict__ Q,
                                                          const float* __restrict__ Km,
                                                          float* __restrict__ att, int Lq) {
  int q = blockIdx.x, bh = blockIdx.y;
  int b = bh >> 3, h = bh & 7;
  int tid = threadIdx.x;
  __shared__ __align__(16) float qv[DHc];
  __shared__ float s[Lc];
  __shared__ float red[256];
  const float* Qrow = Q + ((size_t)b * Lq + q) * Dc + h * DHc;
  if (tid < DHc) qv[tid] = Qrow[tid];
  __syncthreads();
  for (int k = tid; k < Lq; k += 256) {
    const float4* K4 = (const float4*)(Km + ((size_t)b * Lq + k) * Dc + h * DHc);
    const float4* q4 = (const float4*)qv;
    float acc = 0.f;
    #pragma unroll
    for (int i = 0; i < 16; ++i) {
      float4 kv = K4[i], qq = q4[i];
      acc += kv.x * qq.x + kv.y * qq.y + kv.z * qq.z + kv.w * qq.w;
    }
    s[k] = acc * 0.125f;  // 1/sqrt(64)
  }
  __syncthreads();
  float lm = -INFINITY;
  for (int k = tid; k < Lq; k += 256) lm = fmaxf(lm, s[k]);
  red[tid] = lm; __syncthreads();
  #pragma unroll
  for (int off = 128; off > 0; off >>= 1) {
    if (tid < off) red[tid] = fmaxf(red[tid], red[tid + off]);
    __syncthreads();
  }
  float m = red[0]; __syncthreads();
  float ls = 0.f;
  for (int k = tid; k < Lq; k += 256) { float e = expf(s[k] - m); s[k] = e; ls += e; }
  red[tid] = ls; __syncthreads();
  #pragma unroll
  for (int off = 128; off > 0; off >>= 1) {
    if (tid < off) red[tid] += red[tid + off];
    __syncthreads();
  }
  float inv = 1.0f / red[0];
  float* arow = att + ((size_t)bh * Lq + q) * Lq;
  for (int k = tid; k < Lq; k += 256) arow[k] = s[k] * inv;
}

// ---------------- out = attn @ V ----------------
// grid (Lq, Bc), block 512 (thread = output channel)
__global__ __launch_bounds__(512) void attn_av_kernel(const float* __restrict__ att,
                                                      const float* __restrict__ V,
                                                      float* __restrict__ out, int Lq) {
  int q = blockIdx.x, b = blockIdx.y;
  int tid = threadIdx.x;
  int h = tid >> 6;
  __shared__ float sa[Hc * Lc];  // 32KB max
  for (int i = tid; i < Hc * Lq; i += 512) {
    int hh = i / Lq, k = i - hh * Lq;
    sa[i] = att[(((size_t)b * Hc + hh) * Lq + q) * Lq + k];
  }
  __syncthreads();
  const float* sarow = sa + h * Lq;
  const float* Vb = V + (size_t)b * Lq * Dc + tid;
  float acc = 0.f;
  int k = 0;
  for (; k + 3 < Lq; k += 4) {
    acc += sarow[k]     * Vb[(size_t)k * Dc];
    acc += sarow[k + 1] * Vb[(size_t)(k + 1) * Dc];
    acc += sarow[k + 2] * Vb[(size_t)(k + 2) * Dc];
    acc += sarow[k + 3] * Vb[(size_t)(k + 3) * Dc];
  }
  for (; k < Lq; ++k) acc += sarow[k] * Vb[(size_t)k * Dc];
  out[((size_t)b * Lq + q) * Dc + tid] = acc;
}

// ---------------- layernorm: out = LN(alpha*x + res) * g + b ----------------
// grid rows, block 256 (D=512: 2 per thread)
__global__ __launch_bounds__(256) void layernorm_kernel(const float* __restrict__ x,
                                                        const float* __restrict__ res,
                                                        float alpha,
                                                        const float* __restrict__ g,
                                                        const float* __restrict__ bt,
                                                        float* __restrict__ out) {
  int row = blockIdx.x, tid = threadIdx.x;
  const float* xr = x + (size_t)row * Dc;
  float v0 = alpha * xr[tid];
  float v1 = alpha * xr[tid + 256];
  if (res) {
    v0 += res[(size_t)row * Dc + tid];
    v1 += res[(size_t)row * Dc + tid + 256];
  }
  __shared__ float rs[256], rss[256];
  rs[tid] = v0 + v1;
  rss[tid] = v0 * v0 + v1 * v1;
  __syncthreads();
  #pragma unroll
  for (int off = 128; off > 0; off >>= 1) {
    if (tid < off) { rs[tid] += rs[tid + off]; rss[tid] += rss[tid + off]; }
    __syncthreads();
  }
  float mean = rs[0] * (1.0f / Dc);
  float var = rss[0] * (1.0f / Dc) - mean * mean;
  float r = rsqrtf(var + 1e-5f);
  out[(size_t)row * Dc + tid] = (v0 - mean) * r * g[tid] + bt[tid];
  out[(size_t)row * Dc + tid + 256] = (v1 - mean) * r * g[tid + 256] + bt[tid + 256];
}

// ---------------- host ----------------

extern "C" void kernel_launch(void* const* d_in, const int* in_sizes, int n_in,
                              void* d_out, int out_size, void* d_ws, size_t ws_size,
                              hipStream_t stream) {
  const float* x          = (const float*)d_in[0];
  const float* emb_w      = (const float*)d_in[1];
  const float* enc_Wq     = (const float*)d_in[2];
  const float* enc_bq     = (const float*)d_in[3];
  const float* enc_Wk     = (const float*)d_in[4];
  const float* enc_bk     = (const float*)d_in[5];
  const float* enc_Wv     = (const float*)d_in[6];
  const float* enc_bv     = (const float*)d_in[7];
  const float* enc_Wo     = (const float*)d_in[8];
  const float* enc_bo     = (const float*)d_in[9];
  const float* enc_ln_g   = (const float*)d_in[10];
  const float* enc_ln_b   = (const float*)d_in[11];
  const float* dec_Wq     = (const float*)d_in[12];
  const float* dec_bq     = (const float*)d_in[13];
  const float* dec_Wk     = (const float*)d_in[14];
  const float* dec_bk     = (const float*)d_in[15];
  const float* dec_Wv     = (const float*)d_in[16];
  const float* dec_bv     = (const float*)d_in[17];
  const float* dec_Wo     = (const float*)d_in[18];
  const float* dec_bo     = (const float*)d_in[19];
  const float* dconv1_w   = (const float*)d_in[20];
  const float* dconv1_b   = (const float*)d_in[21];
  const float* dconv2_w   = (const float*)d_in[22];
  const float* dconv2_b   = (const float*)d_in[23];
  const float* dln1_g     = (const float*)d_in[24];
  const float* dln1_b     = (const float*)d_in[25];
  const float* dln2_g     = (const float*)d_in[26];
  const float* dln2_b     = (const float*)d_in[27];
  const float* pro_w1     = (const float*)d_in[28];
  const float* pro_b1     = (const float*)d_in[29];
  const float* pro_w2     = (const float*)d_in[30];
  const float* pro_b2     = (const float*)d_in[31];
  const float* mask_token = (const float*)d_in[32];

  float* out = (float*)d_out;
  float* ws  = (float*)d_ws;

  const size_t BLD = (size_t)Bc * Lc * Dc;      // 4,194,304 floats (16 MB)

  // compact 4-slot rotation: total ws use ~64.1 MB
  float* slotA = ws;
  float* slotB = ws + BLD;
  float* slotC = ws + 2 * BLD;
  float* slotD = ws + 3 * BLD;
  float* diffb = ws + 4 * BLD;
  int*   mlist = (int*)(diffb + (size_t)Bc * Lc);
  int*   ulist = mlist + Bc * TRc;

  float* att0 = out;                            // decoder layer-0 att; encoder scratch before that
  float* att1 = out + (size_t)67108864;
  float* att2 = out + (size_t)134217728;
  float* rec  = out + (size_t)201326592;        // 8192*512 floats
  float* attbufs[3] = {att0, att1, att2};
  float* hid  = rec;                            // FFN hidden chunk (2048x2048) == rec size exactly

  // 1. embedding -> A
  embed_kernel<<<dim3(Lc, Bc), Dc, 0, stream>>>(x, emb_w, slotA);
  // 2. diff + select
  diff_kernel<<<Bc * Lc, 64, 0, stream>>>(slotA, diffb);
  select_kernel<<<Bc, Lc, 0, stream>>>(diffb, mlist, ulist);
  // 3. gather unmasked: A -> B   (ex dead after this; mask tokens recompute PE)
  gather_kernel<<<dim3(UNc, Bc), Dc, 0, stream>>>(slotA, ulist, slotB);

  // 4. encoder (3 layers over [B, UN, D]); att probs scratch in att0 region
  int Mu = Bc * UNc;  // 4920
  dim3 ggrid_u(Dc / GBN, (Mu + GBM - 1) / GBM);
  for (int i = 0; i < Ec; ++i) {
    const float* Wq = enc_Wq + (size_t)i * Dc * Dc;  const float* bq = enc_bq + i * Dc;
    const float* Wk = enc_Wk + (size_t)i * Dc * Dc;  const float* bk = enc_bk + i * Dc;
    const float* Wv = enc_Wv + (size_t)i * Dc * Dc;  const float* bv = enc_bv + i * Dc;
    const float* Wo = enc_Wo + (size_t)i * Dc * Dc;  const float* bo = enc_bo + i * Dc;
    // in=B, q=C, k=D, v=A, av->C (q dead), Wo: C->B (u dead after QKV)
    gemm_kernel<<<ggrid_u, 256, 0, stream>>>(slotB, Wq, bq, slotC, Mu, Dc, Dc, 0);
    gemm_kernel<<<ggrid_u, 256, 0, stream>>>(slotB, Wk, bk, slotD, Mu, Dc, Dc, 0);
    gemm_kernel<<<ggrid_u, 256, 0, stream>>>(slotB, Wv, bv, slotA, Mu, Dc, Dc, 0);
    attn_scores_kernel<<<dim3(UNc, Bc * Hc), 256, 0, stream>>>(slotC, slotD, att0, UNc);
    attn_av_kernel<<<dim3(UNc, Bc), 512, 0, stream>>>(att0, slotA, slotC, UNc);
    gemm_kernel<<<ggrid_u, 256, 0, stream>>>(slotC, Wo, bo, slotB, Mu, Dc, Dc, 0);
  }
  layernorm_kernel<<<Mu, 256, 0, stream>>>(slotB, nullptr, 1.0f, enc_ln_g, enc_ln_b, slotC);

  // 5. scatter into full-length token buffer -> A (every position covered: no zero-init)
  scatter_unmasked<<<dim3(UNc, Bc), Dc, 0, stream>>>(slotC, ulist, slotA);
  scatter_masked<<<dim3(TRc, Bc), Dc, 0, stream>>>(mask_token, mlist, slotA);

  // 6. decoder (3 layers over [B, L, D]); att written straight to outputs
  int Md = Bc * Lc;  // 8192
  dim3 ggrid_d(Dc / GBN, Md / GBM);
  float* din = slotA;
  float* fr0 = slotB;  // free slots rotate
  float* fr1 = slotC;
  float* fr2 = slotD;
  for (int i = 0; i < Ec; ++i) {
    const float* Wq = dec_Wq + (size_t)i * Dc * Dc;  const float* bq = dec_bq + i * Dc;
    const float* Wk = dec_Wk + (size_t)i * Dc * Dc;  const float* bk = dec_bk + i * Dc;
    const float* Wv = dec_Wv + (size_t)i * Dc * Dc;  const float* bv = dec_bv + i * Dc;
    const float* Wo = dec_Wo + (size_t)i * Dc * Dc;  const float* bo = dec_bo + i * Dc;
    float* q = fr0; float* k = fr1; float* v = fr2;
    gemm_kernel<<<ggrid_d, 256, 0, stream>>>(din, Wq, bq, q, Md, Dc, Dc, 0);
    gemm_kernel<<<ggrid_d, 256, 0, stream>>>(din, Wk, bk, k, Md, Dc, Dc, 0);
    gemm_kernel<<<ggrid_d, 256, 0, stream>>>(din, Wv, bv, v, Md, Dc, Dc, 0);
    attn_scores_kernel<<<dim3(Lc, Bc * Hc), 256, 0, stream>>>(q, k, attbufs[i], Lc);
    attn_av_kernel<<<dim3(Lc, Bc), 512, 0, stream>>>(attbufs[i], v, q, Lc);  // av -> q (Q dead)
    gemm_kernel<<<ggrid_d, 256, 0, stream>>>(q, Wo, bo, k, Md, Dc, Dc, 0);   // Wo -> k (K dead)
    // rotate: new dx = k; free = {din(old), q, v}
    float* ndin = k;
    fr0 = din; fr1 = q; fr2 = v;
    din = ndin;
  }

  // 7. dx = 2*dx; ln1 -> fr0
  float* lnA = fr0;
  layernorm_kernel<<<Md, 256, 0, stream>>>(din, nullptr, 2.0f, dln1_g, dln1_b, lnA);

  // 8. FFN chunked (hidden in rec region): y -> fr1
  float* ybuf = fr1;
  for (int c = 0; c < 4; ++c) {
    const float* Ain = lnA + (size_t)c * 2048 * Dc;
    float* yout = ybuf + (size_t)c * 2048 * Dc;
    gemm_kernel<<<dim3(DFFc / GBN, 2048 / GBM), 256, 0, stream>>>(Ain, dconv1_w, dconv1_b, hid,
                                                                  2048, DFFc, Dc, 1);
    gemm_kernel<<<dim3(Dc / GBN, 2048 / GBM), 256, 0, stream>>>(hid, dconv2_w, dconv2_b, yout,
                                                                2048, Dc, DFFc, 0);
  }
  // 9. ln2(lnA + y) -> fr2
  float* ln2o = fr2;
  layernorm_kernel<<<Md, 256, 0, stream>>>(lnA, ybuf, 1.0f, dln2_g, dln2_b, ln2o);

  // 10. projection head: sigmoid(gelu(ln2o@w1+b1)@w2+b2) -> rec
  float* g1 = din;  // old dx dead now
  gemm_kernel<<<ggrid_d, 256, 0, stream>>>(ln2o, pro_w1, pro_b1, g1, Md, Dc, Dc, 2);
  gemm_kernel<<<ggrid_d, 256, 0, stream>>>(g1, pro_w2, pro_b2, rec, Md, Dc, Dc, 3);
}

// Round 4
// 11704.527 us; speedup vs baseline: 1.3248x; 1.3248x over previous
//
#include <hip/hip_runtime.h>
#include <math.h>

#define Bc   8
#define Lc   1024
#define CINc 38
#define Dc   512
#define Ec   3
#define Hc   8
#define DHc  64
#define DFFc 2048
#define TRc  409
#define UNc  615
#define UNPc 616   // padded row stride for encoder attention scratch (16B-aligned)

// ---------------- helpers ----------------

__device__ __forceinline__ float pe_val(int pos, int d) {
  int i = d >> 1;
  float div = expf((float)(2 * i) * (-9.210340371976184f / 512.0f)); // -ln(10000)/D
  float ang = (float)pos * div;
  return (d & 1) ? cosf(ang) : sinf(ang);
}

__device__ __forceinline__ float apply_act(float v, int act) {
  if (act == 1) return v > 0.f ? v : 0.f;                       // relu
  if (act == 2) {                                               // gelu (tanh approx, jax default)
    float c = 0.7978845608028654f;
    float t = tanhf(c * (v + 0.044715f * v * v * v));
    return 0.5f * v * (1.0f + t);
  }
  if (act == 3) return 1.0f / (1.0f + expf(-v));                // sigmoid
  return v;
}

// ---------------- embedding: circular conv3 + PE ----------------
// grid (Lc, Bc), block 512
__global__ void embed_kernel(const float* __restrict__ x, const float* __restrict__ w,
                             float* __restrict__ ex) {
  int l = blockIdx.x, b = blockIdx.y, d = threadIdx.x;
  __shared__ float xs[3 * CINc];
  if (d < 3 * CINc) {
    int k = d / CINc, c = d - (d / CINc) * CINc;
    int lsrc = l + k - 1;
    if (lsrc < 0) lsrc += Lc;
    if (lsrc >= Lc) lsrc -= Lc;
    xs[d] = x[((size_t)b * Lc + lsrc) * CINc + c];
  }
  __syncthreads();
  float acc = 0.f;
  #pragma unroll 3
  for (int k = 0; k < 3; ++k)
    for (int c = 0; c < CINc; ++c)
      acc += xs[k * CINc + c] * w[((size_t)(k * CINc + c)) * Dc + d];
  ex[((size_t)b * Lc + l) * Dc + d] = acc + pe_val(l, d);
}

// ---------------- diff: mean_d |ex[l+1]-ex[l]| ----------------
// grid Bc*Lc, block 64 (one wave)
__global__ void diff_kernel(const float* __restrict__ ex, float* __restrict__ diff) {
  int bl = blockIdx.x;
  int l = bl & (Lc - 1);
  int tid = threadIdx.x;
  if (l == Lc - 1) { if (tid == 0) diff[bl] = -1.0f; return; }  // sentinel: score=inf => smallest
  const float* a = ex + (size_t)bl * Dc;
  const float* b = a + Dc;
  float s = 0.f;
  for (int d = tid; d < Dc; d += 64) s += fabsf(b[d] - a[d]);
  #pragma unroll
  for (int off = 32; off > 0; off >>= 1) s += __shfl_down(s, off);
  if (tid == 0) diff[bl] = s * (1.0f / Dc);
}

// ---------------- dual top-k partition by rank ----------------
// grid Bc, block 1024
__global__ void select_kernel(const float* __restrict__ diff, int* __restrict__ mlist,
                              int* __restrict__ ulist) {
  int b = blockIdx.x, l = threadIdx.x;
  __shared__ float ds[Lc];
  __shared__ int flag[Lc];
  ds[l] = diff[(size_t)b * Lc + l];
  __syncthreads();
  float mine = ds[l];
  int rank = 0;
  for (int j = 0; j < Lc; ++j) {
    float o = ds[j];
    rank += (o < mine) || (o == mine && j < l);
  }
  int is_m = (rank < TRc) ? 1 : 0;
  flag[l] = is_m;
  __syncthreads();
  int pre = 0;
  for (int j = 0; j < l; ++j) pre += flag[j];
  if (is_m) mlist[b * TRc + pre] = l;
  else      ulist[b * UNc + (l - pre)] = l;
}

// ---------------- gather unmasked tokens ----------------
// grid (UNc, Bc), block 512
__global__ void gather_kernel(const float* __restrict__ ex, const int* __restrict__ ulist,
                              float* __restrict__ u) {
  int i = blockIdx.x, b = blockIdx.y, d = threadIdx.x;
  int l = ulist[b * UNc + i];
  u[((size_t)b * UNc + i) * Dc + d] = ex[((size_t)b * Lc + l) * Dc + d];
}

// ---------------- scatter ----------------
// grid (UNc, Bc), block 512
__global__ void scatter_unmasked(const float* __restrict__ u, const int* __restrict__ ulist,
                                 float* __restrict__ tokens) {
  int i = blockIdx.x, b = blockIdx.y, d = threadIdx.x;
  int l = ulist[b * UNc + i];
  tokens[((size_t)b * Lc + l) * Dc + d] = u[((size_t)b * UNc + i) * Dc + d];
}
// grid (TRc, Bc), block 512
__global__ void scatter_masked(const float* __restrict__ mtok, const int* __restrict__ mlist,
                               float* __restrict__ tokens) {
  int i = blockIdx.x, b = blockIdx.y, d = threadIdx.x;
  int l = mlist[b * TRc + i];
  tokens[((size_t)b * Lc + l) * Dc + d] = mtok[d] + pe_val(l, d);
}

// ---------------- generic GEMM: C = act(A[MxK] @ W[KxN] + bias) ----------------
// block 256 (16x16 threads, 4x4 per thread => 64x64 tile), K step 16
#define GBM 64
#define GBN 64
#define GBK 16
__global__ __launch_bounds__(256) void gemm_kernel(const float* __restrict__ A,
                                                   const float* __restrict__ W,
                                                   const float* __restrict__ bias,
                                                   float* __restrict__ C,
                                                   int M, int N, int K, int act) {
  __shared__ float As[GBK][GBM + 1];
  __shared__ float Bs[GBK][GBN + 1];
  int tid = threadIdx.x;
  int tx = tid & 15, ty = tid >> 4;
  int rowBase = blockIdx.y * GBM;
  int colBase = blockIdx.x * GBN;
  float acc[4][4] = {{0.f}};
  for (int k0 = 0; k0 < K; k0 += GBK) {
    #pragma unroll
    for (int t = 0; t < 4; ++t) {
      int idx = tid + t * 256;
      int r = idx >> 4, kk = idx & 15;
      int row = rowBase + r;
      As[kk][r] = (row < M) ? A[(size_t)row * K + k0 + kk] : 0.f;
    }
    #pragma unroll
    for (int t = 0; t < 4; ++t) {
      int idx = tid + t * 256;
      int kk = idx >> 6, c = idx & 63;
      Bs[kk][c] = W[(size_t)(k0 + kk) * N + colBase + c];
    }
    __syncthreads();
    #pragma unroll
    for (int kk = 0; kk < GBK; ++kk) {
      float a0 = As[kk][ty * 4 + 0], a1 = As[kk][ty * 4 + 1];
      float a2 = As[kk][ty * 4 + 2], a3 = As[kk][ty * 4 + 3];
      float b0 = Bs[kk][tx * 4 + 0], b1 = Bs[kk][tx * 4 + 1];
      float b2 = Bs[kk][tx * 4 + 2], b3 = Bs[kk][tx * 4 + 3];
      acc[0][0] += a0 * b0; acc[0][1] += a0 * b1; acc[0][2] += a0 * b2; acc[0][3] += a0 * b3;
      acc[1][0] += a1 * b0; acc[1][1] += a1 * b1; acc[1][2] += a1 * b2; acc[1][3] += a1 * b3;
      acc[2][0] += a2 * b0; acc[2][1] += a2 * b1; acc[2][2] += a2 * b2; acc[2][3] += a2 * b3;
      acc[3][0] += a3 * b0; acc[3][1] += a3 * b1; acc[3][2] += a3 * b2; acc[3][3] += a3 * b3;
    }
    __syncthreads();
  }
  #pragma unroll
  for (int i = 0; i < 4; ++i) {
    int row = rowBase + ty * 4 + i;
    if (row >= M) continue;
    #pragma unroll
    for (int j = 0; j < 4; ++j) {
      int col = colBase + tx * 4 + j;
      float v = acc[i][j] + (bias ? bias[col] : 0.f);
      C[(size_t)row * N + col] = apply_act(v, act);
    }
  }
}

// ---------------- attention QK^T: batched tiled GEMM ----------------
// S[bh, q, k] = 0.125 * sum_d Q[b,q,h*64+d] * K[b,k,h*64+d]
// grid (ceil(Lq/64), ceil(Lq/64), B*H), block 256. att rows have stride Lsr.
__global__ __launch_bounds__(256) void attn_qk_kernel(const float* __restrict__ Q,
                                                      const float* __restrict__ Km,
                                                      float* __restrict__ att,
                                                      int Lq, int Lsr) {
  int bh = blockIdx.z;
  int b = bh >> 3, h = bh & 7;
  int qbase = blockIdx.y * 64, kbase = blockIdx.x * 64;
  __shared__ float Qs[DHc][65];   // [d][q-row]
  __shared__ float Ks[DHc][65];   // [d][k-row]
  int tid = threadIdx.x;
  int tx = tid & 15, ty = tid >> 4;
  // load Q tile: 64 rows x 64 dims, float4 along dim
  #pragma unroll
  for (int t = 0; t < 4; ++t) {
    int idx4 = tid + t * 256;            // 0..1023
    int c4 = idx4 & 15, r = idx4 >> 4;   // c4: float4 idx in dim, r: row 0..63
    int row = qbase + r;
    float4 v = make_float4(0.f, 0.f, 0.f, 0.f);
    if (row < Lq)
      v = *(const float4*)(Q + ((size_t)b * Lq + row) * Dc + h * DHc + c4 * 4);
    Qs[c4 * 4 + 0][r] = v.x; Qs[c4 * 4 + 1][r] = v.y;
    Qs[c4 * 4 + 2][r] = v.z; Qs[c4 * 4 + 3][r] = v.w;
  }
  #pragma unroll
  for (int t = 0; t < 4; ++t) {
    int idx4 = tid + t * 256;
    int c4 = idx4 & 15, r = idx4 >> 4;
    int row = kbase + r;
    float4 v = make_float4(0.f, 0.f, 0.f, 0.f);
    if (row < Lq)
      v = *(const float4*)(Km + ((size_t)b * Lq + row) * Dc + h * DHc + c4 * 4);
    Ks[c4 * 4 + 0][r] = v.x; Ks[c4 * 4 + 1][r] = v.y;
    Ks[c4 * 4 + 2][r] = v.z; Ks[c4 * 4 + 3][r] = v.w;
  }
  __syncthreads();
  float acc[4][4] = {{0.f}};
  #pragma unroll
  for (int kk = 0; kk < DHc; ++kk) {
    float a0 = Qs[kk][ty * 4 + 0], a1 = Qs[kk][ty * 4 + 1];
    float a2 = Qs[kk][ty * 4 + 2], a3 = Qs[kk][ty * 4 + 3];
    float b0 = Ks[kk][tx * 4 + 0], b1 = Ks[kk][tx * 4 + 1];
    float b2 = Ks[kk][tx * 4 + 2], b3 = Ks[kk][tx * 4 + 3];
    acc[0][0] += a0 * b0; acc[0][1] += a0 * b1; acc[0][2] += a0 * b2; acc[0][3] += a0 * b3;
    acc[1][0] += a1 * b0; acc[1][1] += a1 * b1; acc[1][2] += a1 * b2; acc[1][3] += a1 * b3;
    acc[2][0] += a2 * b0; acc[2][1] += a2 * b1; acc[2][2] += a2 * b2; acc[2][3] += a2 * b3;
    acc[3][0] += a3 * b0; acc[3][1] += a3 * b1; acc[3][2] += a3 * b2; acc[3][3] += a3 * b3;
  }
  #pragma unroll
  for (int i = 0; i < 4; ++i) {
    int q = qbase + ty * 4 + i;
    if (q >= Lq) continue;
    #pragma unroll
    for (int j = 0; j < 4; ++j) {
      int k = kbase + tx * 4 + j;
      if (k >= Lq) continue;
      att[((size_t)bh * Lq + q) * Lsr + k] = acc[i][j] * 0.125f;
    }
  }
}

// ---------------- row softmax (in place); zeroes padding tail ----------------
// grid (Lq, B*H), block 256
__global__ __launch_bounds__(256) void softmax_kernel(float* __restrict__ att, int Lq, int Lsr) {
  int q = blockIdx.x, bh = blockIdx.y;
  int tid = threadIdx.x;
  __shared__ float s[Lc];
  __shared__ float red[256];
  float* arow = att + ((size_t)bh * Lq + q) * Lsr;
  float lm = -INFINITY;
  for (int k = tid; k < Lq; k += 256) { float v = arow[k]; s[k] = v; lm = fmaxf(lm, v); }
  red[tid] = lm; __syncthreads();
  #pragma unroll
  for (int off = 128; off > 0; off >>= 1) {
    if (tid < off) red[tid] = fmaxf(red[tid], red[tid + off]);
    __syncthreads();
  }
  float m = red[0]; __syncthreads();
  float ls = 0.f;
  for (int k = tid; k < Lq; k += 256) { float e = expf(s[k] - m); s[k] = e; ls += e; }
  red[tid] = ls; __syncthreads();
  #pragma unroll
  for (int off = 128; off > 0; off >>= 1) {
    if (tid < off) red[tid] += red[tid + off];
    __syncthreads();
  }
  float inv = 1.0f / red[0];
  for (int k = tid; k < Lq; k += 256) arow[k] = s[k] * inv;
  for (int k = Lq + tid; k < Lsr; k += 256) arow[k] = 0.f;   // zero pad for AV float4 loads
}

// ---------------- attention AV: batched tiled GEMM ----------------
// O[b,q,h*64+c] = sum_k P[bh,q,k] * V[b,k,h*64+c]
// grid (1, ceil(Lq/64), B*H), block 256
__global__ __launch_bounds__(256) void attn_av_kernel(const float* __restrict__ P,
                                                      const float* __restrict__ V,
                                                      float* __restrict__ O,
                                                      int Lq, int Lsr) {
  int bh = blockIdx.z;
  int b = bh >> 3, h = bh & 7;
  int qbase = blockIdx.y * 64;
  __shared__ float As[32][65];   // [k][q-row]
  __shared__ float Bs[32][65];   // [k][c]
  int tid = threadIdx.x;
  int tx = tid & 15, ty = tid >> 4;
  float acc[4][4] = {{0.f}};
  int nk = (Lq + 31) & ~31;
  for (int k0 = 0; k0 < nk; k0 += 32) {
    // P tile: 64 q-rows x 32 ks (padding cols are zeroed by softmax)
    #pragma unroll
    for (int t = 0; t < 2; ++t) {
      int idx4 = tid + t * 256;            // 0..511
      int k4 = idx4 & 7, r = idx4 >> 3;    // k4: float4 in k, r: q-row
      int q = qbase + r;
      float4 v = make_float4(0.f, 0.f, 0.f, 0.f);
      if (q < Lq && k0 + k4 * 4 < Lsr)
        v = *(const float4*)(P + ((size_t)bh * Lq + q) * Lsr + k0 + k4 * 4);
      As[k4 * 4 + 0][r] = v.x; As[k4 * 4 + 1][r] = v.y;
      As[k4 * 4 + 2][r] = v.z; As[k4 * 4 + 3][r] = v.w;
    }
    // V tile: 32 k-rows x 64 cols
    #pragma unroll
    for (int t = 0; t < 2; ++t) {
      int idx4 = tid + t * 256;
      int c4 = idx4 & 15, kk = idx4 >> 4;  // c4: float4 in c, kk: k-row 0..31
      float4 v = make_float4(0.f, 0.f, 0.f, 0.f);
      if (k0 + kk < Lq)
        v = *(const float4*)(V + ((size_t)b * Lq + k0 + kk) * Dc + h * DHc + c4 * 4);
      Bs[kk][c4 * 4 + 0] = v.x; Bs[kk][c4 * 4 + 1] = v.y;
      Bs[kk][c4 * 4 + 2] = v.z; Bs[kk][c4 * 4 + 3] = v.w;
    }
    __syncthreads();
    #pragma unroll
    for (int kk = 0; kk < 32; ++kk) {
      float a0 = As[kk][ty * 4 + 0], a1 = As[kk][ty * 4 + 1];
      float a2 = As[kk][ty * 4 + 2], a3 = As[kk][ty * 4 + 3];
      float b0 = Bs[kk][tx * 4 + 0], b1 = Bs[kk][tx * 4 + 1];
      float b2 = Bs[kk][tx * 4 + 2], b3 = Bs[kk][tx * 4 + 3];
      acc[0][0] += a0 * b0; acc[0][1] += a0 * b1; acc[0][2] += a0 * b2; acc[0][3] += a0 * b3;
      acc[1][0] += a1 * b0; acc[1][1] += a1 * b1; acc[1][2] += a1 * b2; acc[1][3] += a1 * b3;
      acc[2][0] += a2 * b0; acc[2][1] += a2 * b1; acc[2][2] += a2 * b2; acc[2][3] += a2 * b3;
      acc[3][0] += a3 * b0; acc[3][1] += a3 * b1; acc[3][2] += a3 * b2; acc[3][3] += a3 * b3;
    }
    __syncthreads();
  }
  #pragma unroll
  for (int i = 0; i < 4; ++i) {
    int q = qbase + ty * 4 + i;
    if (q >= Lq) continue;
    #pragma unroll
    for (int j = 0; j < 4; ++j) {
      int c = tx * 4 + j;
      O[((size_t)b * Lq + q) * Dc + h * DHc + c] = acc[i][j];
    }
  }
}

// ---------------- layernorm: out = LN(alpha*x + res) * g + b ----------------
// grid rows, block 256 (D=512: 2 per thread)
__global__ __launch_bounds__(256) void layernorm_kernel(const float* __restrict__ x,
                                                        const float* __restrict__ res,
                                                        float alpha,
                                                        const float* __restrict__ g,
                                                        const float* __restrict__ bt,
                                                        float* __restrict__ out) {
  int row = blockIdx.x, tid = threadIdx.x;
  const float* xr = x + (size_t)row * Dc;
  float v0 = alpha * xr[tid];
  float v1 = alpha * xr[tid + 256];
  if (res) {
    v0 += res[(size_t)row * Dc + tid];
    v1 += res[(size_t)row * Dc + tid + 256];
  }
  __shared__ float rs[256], rss[256];
  rs[tid] = v0 + v1;
  rss[tid] = v0 * v0 + v1 * v1;
  __syncthreads();
  #pragma unroll
  for (int off = 128; off > 0; off >>= 1) {
    if (tid < off) { rs[tid] += rs[tid + off]; rss[tid] += rss[tid + off]; }
    __syncthreads();
  }
  float mean = rs[0] * (1.0f / Dc);
  float var = rss[0] * (1.0f / Dc) - mean * mean;
  float r = rsqrtf(var + 1e-5f);
  out[(size_t)row * Dc + tid] = (v0 - mean) * r * g[tid] + bt[tid];
  out[(size_t)row * Dc + tid + 256] = (v1 - mean) * r * g[tid + 256] + bt[tid + 256];
}

// ---------------- host ----------------

extern "C" void kernel_launch(void* const* d_in, const int* in_sizes, int n_in,
                              void* d_out, int out_size, void* d_ws, size_t ws_size,
                              hipStream_t stream) {
  const float* x          = (const float*)d_in[0];
  const float* emb_w      = (const float*)d_in[1];
  const float* enc_Wq     = (const float*)d_in[2];
  const float* enc_bq     = (const float*)d_in[3];
  const float* enc_Wk     = (const float*)d_in[4];
  const float* enc_bk     = (const float*)d_in[5];
  const float* enc_Wv     = (const float*)d_in[6];
  const float* enc_bv     = (const float*)d_in[7];
  const float* enc_Wo     = (const float*)d_in[8];
  const float* enc_bo     = (const float*)d_in[9];
  const float* enc_ln_g   = (const float*)d_in[10];
  const float* enc_ln_b   = (const float*)d_in[11];
  const float* dec_Wq     = (const float*)d_in[12];
  const float* dec_bq     = (const float*)d_in[13];
  const float* dec_Wk     = (const float*)d_in[14];
  const float* dec_bk     = (const float*)d_in[15];
  const float* dec_Wv     = (const float*)d_in[16];
  const float* dec_bv     = (const float*)d_in[17];
  const float* dec_Wo     = (const float*)d_in[18];
  const float* dec_bo     = (const float*)d_in[19];
  const float* dconv1_w   = (const float*)d_in[20];
  const float* dconv1_b   = (const float*)d_in[21];
  const float* dconv2_w   = (const float*)d_in[22];
  const float* dconv2_b   = (const float*)d_in[23];
  const float* dln1_g     = (const float*)d_in[24];
  const float* dln1_b     = (const float*)d_in[25];
  const float* dln2_g     = (const float*)d_in[26];
  const float* dln2_b     = (const float*)d_in[27];
  const float* pro_w1     = (const float*)d_in[28];
  const float* pro_b1     = (const float*)d_in[29];
  const float* pro_w2     = (const float*)d_in[30];
  const float* pro_b2     = (const float*)d_in[31];
  const float* mask_token = (const float*)d_in[32];

  float* out = (float*)d_out;
  float* ws  = (float*)d_ws;

  const size_t BLD = (size_t)Bc * Lc * Dc;      // 4,194,304 floats (16 MB)

  // compact 4-slot rotation: total ws use ~64.1 MB
  float* slotA = ws;
  float* slotB = ws + BLD;
  float* slotC = ws + 2 * BLD;
  float* slotD = ws + 3 * BLD;
  float* diffb = ws + 4 * BLD;
  int*   mlist = (int*)(diffb + (size_t)Bc * Lc);
  int*   ulist = mlist + Bc * TRc;

  float* att0 = out;                            // decoder layer-0 att; encoder scratch before that
  float* att1 = out + (size_t)67108864;
  float* att2 = out + (size_t)134217728;
  float* rec  = out + (size_t)201326592;        // 8192*512 floats
  float* attbufs[3] = {att0, att1, att2};
  float* hid  = rec;                            // FFN hidden chunk (2048x2048) == rec size exactly

  // 1. embedding -> A
  embed_kernel<<<dim3(Lc, Bc), Dc, 0, stream>>>(x, emb_w, slotA);
  // 2. diff + select
  diff_kernel<<<Bc * Lc, 64, 0, stream>>>(slotA, diffb);
  select_kernel<<<Bc, Lc, 0, stream>>>(diffb, mlist, ulist);
  // 3. gather unmasked: A -> B   (ex dead after this; mask tokens recompute PE)
  gather_kernel<<<dim3(UNc, Bc), Dc, 0, stream>>>(slotA, ulist, slotB);

  // 4. encoder (3 layers over [B, UN, D]); att probs scratch (padded stride) in att0 region
  int Mu = Bc * UNc;  // 4920
  dim3 ggrid_u(Dc / GBN, (Mu + GBM - 1) / GBM);
  int uT = (UNc + 63) / 64;  // 10 tiles
  for (int i = 0; i < Ec; ++i) {
    const float* Wq = enc_Wq + (size_t)i * Dc * Dc;  const float* bq = enc_bq + i * Dc;
    const float* Wk = enc_Wk + (size_t)i * Dc * Dc;  const float* bk = enc_bk + i * Dc;
    const float* Wv = enc_Wv + (size_t)i * Dc * Dc;  const float* bv = enc_bv + i * Dc;
    const float* Wo = enc_Wo + (size_t)i * Dc * Dc;  const float* bo = enc_bo + i * Dc;
    // in=B, q=C, k=D, v=A, av->C (q dead), Wo: C->B
    gemm_kernel<<<ggrid_u, 256, 0, stream>>>(slotB, Wq, bq, slotC, Mu, Dc, Dc, 0);
    gemm_kernel<<<ggrid_u, 256, 0, stream>>>(slotB, Wk, bk, slotD, Mu, Dc, Dc, 0);
    gemm_kernel<<<ggrid_u, 256, 0, stream>>>(slotB, Wv, bv, slotA, Mu, Dc, Dc, 0);
    attn_qk_kernel<<<dim3(uT, uT, Bc * Hc), 256, 0, stream>>>(slotC, slotD, att0, UNc, UNPc);
    softmax_kernel<<<dim3(UNc, Bc * Hc), 256, 0, stream>>>(att0, UNc, UNPc);
    attn_av_kernel<<<dim3(1, uT, Bc * Hc), 256, 0, stream>>>(att0, slotA, slotC, UNc, UNPc);
    gemm_kernel<<<ggrid_u, 256, 0, stream>>>(slotC, Wo, bo, slotB, Mu, Dc, Dc, 0);
  }
  layernorm_kernel<<<Mu, 256, 0, stream>>>(slotB, nullptr, 1.0f, enc_ln_g, enc_ln_b, slotC);

  // 5. scatter into full-length token buffer -> A (every position covered: no zero-init)
  scatter_unmasked<<<dim3(UNc, Bc), Dc, 0, stream>>>(slotC, ulist, slotA);
  scatter_masked<<<dim3(TRc, Bc), Dc, 0, stream>>>(mask_token, mlist, slotA);

  // 6. decoder (3 layers over [B, L, D]); att written straight to outputs
  int Md = Bc * Lc;  // 8192
  dim3 ggrid_d(Dc / GBN, Md / GBM);
  float* din = slotA;
  float* fr0 = slotB;  // free slots rotate
  float* fr1 = slotC;
  float* fr2 = slotD;
  for (int i = 0; i < Ec; ++i) {
    const float* Wq = dec_Wq + (size_t)i * Dc * Dc;  const float* bq = dec_bq + i * Dc;
    const float* Wk = dec_Wk + (size_t)i * Dc * Dc;  const float* bk = dec_bk + i * Dc;
    const float* Wv = dec_Wv + (size_t)i * Dc * Dc;  const float* bv = dec_bv + i * Dc;
    const float* Wo = dec_Wo + (size_t)i * Dc * Dc;  const float* bo = dec_bo + i * Dc;
    float* q = fr0; float* k = fr1; float* v = fr2;
    gemm_kernel<<<ggrid_d, 256, 0, stream>>>(din, Wq, bq, q, Md, Dc, Dc, 0);
    gemm_kernel<<<ggrid_d, 256, 0, stream>>>(din, Wk, bk, k, Md, Dc, Dc, 0);
    gemm_kernel<<<ggrid_d, 256, 0, stream>>>(din, Wv, bv, v, Md, Dc, Dc, 0);
    attn_qk_kernel<<<dim3(16, 16, Bc * Hc), 256, 0, stream>>>(q, k, attbufs[i], Lc, Lc);
    softmax_kernel<<<dim3(Lc, Bc * Hc), 256, 0, stream>>>(attbufs[i], Lc, Lc);
    attn_av_kernel<<<dim3(1, 16, Bc * Hc), 256, 0, stream>>>(attbufs[i], v, q, Lc, Lc);  // -> q
    gemm_kernel<<<ggrid_d, 256, 0, stream>>>(q, Wo, bo, k, Md, Dc, Dc, 0);   // Wo -> k
    // rotate: new dx = k; free = {din(old), q, v}
    float* ndin = k;
    fr0 = din; fr1 = q; fr2 = v;
    din = ndin;
  }

  // 7. dx = 2*dx; ln1 -> fr0
  float* lnA = fr0;
  layernorm_kernel<<<Md, 256, 0, stream>>>(din, nullptr, 2.0f, dln1_g, dln1_b, lnA);

  // 8. FFN chunked (hidden in rec region): y -> fr1
  float* ybuf = fr1;
  for (int c = 0; c < 4; ++c) {
    const float* Ain = lnA + (size_t)c * 2048 * Dc;
    float* yout = ybuf + (size_t)c * 2048 * Dc;
    gemm_kernel<<<dim3(DFFc / GBN, 2048 / GBM), 256, 0, stream>>>(Ain, dconv1_w, dconv1_b, hid,
                                                                  2048, DFFc, Dc, 1);
    gemm_kernel<<<dim3(Dc / GBN, 2048 / GBM), 256, 0, stream>>>(hid, dconv2_w, dconv2_b, yout,
                                                                2048, Dc, DFFc, 0);
  }
  // 9. ln2(lnA + y) -> fr2
  float* ln2o = fr2;
  layernorm_kernel<<<Md, 256, 0, stream>>>(lnA, ybuf, 1.0f, dln2_g, dln2_b, ln2o);

  // 10. projection head: sigmoid(gelu(ln2o@w1+b1)@w2+b2) -> rec
  float* g1 = din;  // old dx dead now
  gemm_kernel<<<ggrid_d, 256, 0, stream>>>(ln2o, pro_w1, pro_b1, g1, Md, Dc, Dc, 2);
  gemm_kernel<<<ggrid_d, 256, 0, stream>>>(g1, pro_w2, pro_b2, rec, Md, Dc, Dc, 3);
}

// Round 6
// 7219.261 us; speedup vs baseline: 2.1479x; 1.6213x over previous
//
#include <hip/hip_runtime.h>
#include <math.h>

#define Bc   8
#define Lc   1024
#define CINc 38
#define Dc   512
#define Ec   3
#define Hc   8
#define DHc  64
#define DFFc 2048
#define TRc  409
#define UNc  615
#define UNPc 616   // padded row stride for encoder attention scratch (16B-aligned)

typedef __attribute__((ext_vector_type(8))) short bf16x8;
typedef __attribute__((ext_vector_type(4))) short s16x4;
typedef __attribute__((ext_vector_type(4))) float f32x4;

// ---------------- helpers ----------------

__device__ __forceinline__ float pe_val(int pos, int d) {
  int i = d >> 1;
  float div = expf((float)(2 * i) * (-9.210340371976184f / 512.0f)); // -ln(10000)/D
  float ang = (float)pos * div;
  return (d & 1) ? cosf(ang) : sinf(ang);
}

__device__ __forceinline__ float apply_act(float v, int act) {
  if (act == 1) return v > 0.f ? v : 0.f;                       // relu
  if (act == 2) {                                               // gelu (tanh approx, jax default)
    float c = 0.7978845608028654f;
    float t = tanhf(c * (v + 0.044715f * v * v * v));
    return 0.5f * v * (1.0f + t);
  }
  if (act == 3) return 1.0f / (1.0f + expf(-v));                // sigmoid
  return v;
}

// split f32 into hi/lo bf16 (truncation; |err| ~ 2^-16 relative)
__device__ __forceinline__ void split2(float x, short& h, short& l) {
  unsigned u = __float_as_uint(x);
  h = (short)(u >> 16);
  float hf = __uint_as_float(u & 0xFFFF0000u);
  l = (short)(__float_as_uint(x - hf) >> 16);
}

// ---------------- embedding: circular conv3 + PE ----------------
// grid (Lc, Bc), block 512
__global__ void embed_kernel(const float* __restrict__ x, const float* __restrict__ w,
                             float* __restrict__ ex) {
  int l = blockIdx.x, b = blockIdx.y, d = threadIdx.x;
  __shared__ float xs[3 * CINc];
  if (d < 3 * CINc) {
    int k = d / CINc, c = d - (d / CINc) * CINc;
    int lsrc = l + k - 1;
    if (lsrc < 0) lsrc += Lc;
    if (lsrc >= Lc) lsrc -= Lc;
    xs[d] = x[((size_t)b * Lc + lsrc) * CINc + c];
  }
  __syncthreads();
  float acc = 0.f;
  #pragma unroll 3
  for (int k = 0; k < 3; ++k)
    for (int c = 0; c < CINc; ++c)
      acc += xs[k * CINc + c] * w[((size_t)(k * CINc + c)) * Dc + d];
  ex[((size_t)b * Lc + l) * Dc + d] = acc + pe_val(l, d);
}

// ---------------- diff: mean_d |ex[l+1]-ex[l]| ----------------
__global__ void diff_kernel(const float* __restrict__ ex, float* __restrict__ diff) {
  int bl = blockIdx.x;
  int l = bl & (Lc - 1);
  int tid = threadIdx.x;
  if (l == Lc - 1) { if (tid == 0) diff[bl] = -1.0f; return; }  // sentinel: score=inf => smallest
  const float* a = ex + (size_t)bl * Dc;
  const float* b = a + Dc;
  float s = 0.f;
  for (int d = tid; d < Dc; d += 64) s += fabsf(b[d] - a[d]);
  #pragma unroll
  for (int off = 32; off > 0; off >>= 1) s += __shfl_down(s, off);
  if (tid == 0) diff[bl] = s * (1.0f / Dc);
}

// ---------------- dual top-k partition by rank ----------------
__global__ void select_kernel(const float* __restrict__ diff, int* __restrict__ mlist,
                              int* __restrict__ ulist) {
  int b = blockIdx.x, l = threadIdx.x;
  __shared__ float ds[Lc];
  __shared__ int flag[Lc];
  ds[l] = diff[(size_t)b * Lc + l];
  __syncthreads();
  float mine = ds[l];
  int rank = 0;
  for (int j = 0; j < Lc; ++j) {
    float o = ds[j];
    rank += (o < mine) || (o == mine && j < l);
  }
  int is_m = (rank < TRc) ? 1 : 0;
  flag[l] = is_m;
  __syncthreads();
  int pre = 0;
  for (int j = 0; j < l; ++j) pre += flag[j];
  if (is_m) mlist[b * TRc + pre] = l;
  else      ulist[b * UNc + (l - pre)] = l;
}

// ---------------- gather / scatter ----------------
__global__ void gather_kernel(const float* __restrict__ ex, const int* __restrict__ ulist,
                              float* __restrict__ u) {
  int i = blockIdx.x, b = blockIdx.y, d = threadIdx.x;
  int l = ulist[b * UNc + i];
  u[((size_t)b * UNc + i) * Dc + d] = ex[((size_t)b * Lc + l) * Dc + d];
}
__global__ void scatter_unmasked(const float* __restrict__ u, const int* __restrict__ ulist,
                                 float* __restrict__ tokens) {
  int i = blockIdx.x, b = blockIdx.y, d = threadIdx.x;
  int l = ulist[b * UNc + i];
  tokens[((size_t)b * Lc + l) * Dc + d] = u[((size_t)b * UNc + i) * Dc + d];
}
__global__ void scatter_masked(const float* __restrict__ mtok, const int* __restrict__ mlist,
                               float* __restrict__ tokens) {
  int i = blockIdx.x, b = blockIdx.y, d = threadIdx.x;
  int l = mlist[b * TRc + i];
  tokens[((size_t)b * Lc + l) * Dc + d] = mtok[d] + pe_val(l, d);
}

// ---------------- MFMA split-bf16 batched GEMM ----------------
// C = act(scale * A @ B + bias).  A: [M x K] f32 (stride lda).
// BT=0: B is W [K x N] (stride ldw).  BT=1: B is K-matrix [N x K] (stride ldw), i.e. C=A@B^T.
// Batch: grid.z = z; per-operand offset = (z>>3)*s?b + (z&7)*s?h.
// Tile: 128 x TN, K-step 32, 4 waves (2x2), per-wave 64 x TN/2 via 16x16x32 MFMA.
// Split-bf16: x = hi + lo; product = hi*hi + lo*hi + hi*lo (3 MFMAs, ~1.5e-5 rel err).
template<int TN>
__global__ __launch_bounds__(256) void mfma_gemm(
    const float* __restrict__ Ab, const float* __restrict__ Wb,
    const float* __restrict__ bias, float* __restrict__ Cb,
    int M, int N, int KA, int KW, int lda, int ldw, int ldc,
    size_t sAb, size_t sAh, size_t sWb, size_t sWh, size_t sCb, size_t sCh,
    int BT, int act, float scale)
{
  constexpr int TM = 128, KS = 32, LK = 40;   // LK: padded k-stride (bf16) -> 80B rows, 16B aligned
  constexpr int FN = TN / 32;                 // n-frags per wave
  __shared__ __align__(16) short AsH[TM][LK], AsL[TM][LK];
  __shared__ __align__(16) short WsH[TN][LK], WsL[TN][LK];
  int z = blockIdx.z, zb = z >> 3, zh = z & 7;
  const float* A = Ab + zb * sAb + zh * sAh;
  const float* W = Wb + zb * sWb + zh * sWh;
  float*       C = Cb + zb * sCb + zh * sCh;
  int tid = threadIdx.x, lane = tid & 63, w = tid >> 6;
  int ln15 = lane & 15, lg = lane >> 4;
  int rowBase = blockIdx.y * TM, colBase = blockIdx.x * TN;
  int wm = (w >> 1) * 64, wn = (w & 1) * (TN / 2);

  f32x4 acc[4][FN];
  #pragma unroll
  for (int i = 0; i < 4; ++i)
    #pragma unroll
    for (int j = 0; j < FN; ++j) acc[i][j] = (f32x4){0.f, 0.f, 0.f, 0.f};

  for (int k0 = 0; k0 < KA; k0 += KS) {
    // ---- stage A tile (TM x KS): f32 -> hi/lo bf16, rows contiguous in k ----
    for (int v = tid; v < TM * 8; v += 256) {
      int r = v >> 3, kq = v & 7;
      int gr = rowBase + r, gk = k0 + kq * 4;
      float4 f = make_float4(0.f, 0.f, 0.f, 0.f);
      if (gr < M && gk < KA) f = *(const float4*)(A + (size_t)gr * lda + gk);
      float fv[4] = {f.x, f.y, f.z, f.w};
      s16x4 hh, ll;
      #pragma unroll
      for (int i = 0; i < 4; ++i) { short h, l; split2(fv[i], h, l); hh[i] = h; ll[i] = l; }
      *(s16x4*)&AsH[r][kq * 4] = hh;
      *(s16x4*)&AsL[r][kq * 4] = ll;
    }
    // ---- stage B tile ----
    if (BT) {
      // B rows are output columns (C = A@B^T): same contiguous-k staging as A
      for (int v = tid; v < TN * 8; v += 256) {
        int r = v >> 3, kq = v & 7;
        int gr = colBase + r, gk = k0 + kq * 4;
        float4 f = make_float4(0.f, 0.f, 0.f, 0.f);
        if (gr < N && gk < KA) f = *(const float4*)(W + (size_t)gr * ldw + gk);
        float fv[4] = {f.x, f.y, f.z, f.w};
        s16x4 hh, ll;
        #pragma unroll
        for (int i = 0; i < 4; ++i) { short h, l; split2(fv[i], h, l); hh[i] = h; ll[i] = l; }
        *(s16x4*)&WsH[r][kq * 4] = hh;
        *(s16x4*)&WsL[r][kq * 4] = ll;
      }
    } else {
      // W [K x N] row-major -> transposed LDS Wt[n][k]
      constexpr int NQ = TN / 4;
      for (int v = tid; v < KS * NQ; v += 256) {
        int k = v / NQ, n4 = v % NQ;
        int gk = k0 + k;
        float4 f = make_float4(0.f, 0.f, 0.f, 0.f);
        if (gk < KW) f = *(const float4*)(W + (size_t)gk * ldw + colBase + n4 * 4);
        float fv[4] = {f.x, f.y, f.z, f.w};
        #pragma unroll
        for (int i = 0; i < 4; ++i) {
          short h, l; split2(fv[i], h, l);
          WsH[n4 * 4 + i][k] = h;
          WsL[n4 * 4 + i][k] = l;
        }
      }
    }
    __syncthreads();
    // ---- MFMA: per-wave 4 x FN fragments, 3 MFMAs each (split-bf16) ----
    bf16x8 aH[4], aL[4];
    #pragma unroll
    for (int mi = 0; mi < 4; ++mi) {
      aH[mi] = *(const bf16x8*)&AsH[wm + mi * 16 + ln15][lg * 8];
      aL[mi] = *(const bf16x8*)&AsL[wm + mi * 16 + ln15][lg * 8];
    }
    #pragma unroll
    for (int nj = 0; nj < FN; ++nj) {
      bf16x8 bH = *(const bf16x8*)&WsH[wn + nj * 16 + ln15][lg * 8];
      bf16x8 bL = *(const bf16x8*)&WsL[wn + nj * 16 + ln15][lg * 8];
      #pragma unroll
      for (int mi = 0; mi < 4; ++mi) {
        acc[mi][nj] = __builtin_amdgcn_mfma_f32_16x16x32_bf16(aH[mi], bH, acc[mi][nj], 0, 0, 0);
        acc[mi][nj] = __builtin_amdgcn_mfma_f32_16x16x32_bf16(aL[mi], bH, acc[mi][nj], 0, 0, 0);
        acc[mi][nj] = __builtin_amdgcn_mfma_f32_16x16x32_bf16(aH[mi], bL, acc[mi][nj], 0, 0, 0);
      }
    }
    __syncthreads();
  }
  // ---- epilogue: C/D layout col=lane&15, row=(lane>>4)*4+reg (HW-verified) ----
  #pragma unroll
  for (int mi = 0; mi < 4; ++mi) {
    #pragma unroll
    for (int nj = 0; nj < FN; ++nj) {
      int col = colBase + wn + nj * 16 + ln15;
      if (col >= N) continue;
      int row0 = rowBase + wm + mi * 16 + lg * 4;
      float bv = bias ? bias[col] : 0.f;
      #pragma unroll
      for (int rr = 0; rr < 4; ++rr) {
        int row = row0 + rr;
        if (row < M)
          C[(size_t)row * ldc + col] = apply_act(acc[mi][nj][rr] * scale + bv, act);
      }
    }
  }
}

// ---------------- row softmax (in place); zeroes padding tail ----------------
// grid (Lq, B*H), block 256
__global__ __launch_bounds__(256) void softmax_kernel(float* __restrict__ att, int Lq, int Lsr) {
  int q = blockIdx.x, bh = blockIdx.y;
  int tid = threadIdx.x;
  __shared__ float s[Lc];
  __shared__ float red[256];
  float* arow = att + ((size_t)bh * Lq + q) * Lsr;
  float lm = -INFINITY;
  for (int k = tid; k < Lq; k += 256) { float v = arow[k]; s[k] = v; lm = fmaxf(lm, v); }
  red[tid] = lm; __syncthreads();
  #pragma unroll
  for (int off = 128; off > 0; off >>= 1) {
    if (tid < off) red[tid] = fmaxf(red[tid], red[tid + off]);
    __syncthreads();
  }
  float m = red[0]; __syncthreads();
  float ls = 0.f;
  for (int k = tid; k < Lq; k += 256) { float e = expf(s[k] - m); s[k] = e; ls += e; }
  red[tid] = ls; __syncthreads();
  #pragma unroll
  for (int off = 128; off > 0; off >>= 1) {
    if (tid < off) red[tid] += red[tid + off];
    __syncthreads();
  }
  float inv = 1.0f / red[0];
  for (int k = tid; k < Lq; k += 256) arow[k] = s[k] * inv;
  for (int k = Lq + tid; k < Lsr; k += 256) arow[k] = 0.f;   // zero pad for AV k-reads
}

// ---------------- layernorm: out = LN(alpha*x + res) * g + b ----------------
__global__ __launch_bounds__(256) void layernorm_kernel(const float* __restrict__ x,
                                                        const float* __restrict__ res,
                                                        float alpha,
                                                        const float* __restrict__ g,
                                                        const float* __restrict__ bt,
                                                        float* __restrict__ out) {
  int row = blockIdx.x, tid = threadIdx.x;
  const float* xr = x + (size_t)row * Dc;
  float v0 = alpha * xr[tid];
  float v1 = alpha * xr[tid + 256];
  if (res) {
    v0 += res[(size_t)row * Dc + tid];
    v1 += res[(size_t)row * Dc + tid + 256];
  }
  __shared__ float rs[256], rss[256];
  rs[tid] = v0 + v1;
  rss[tid] = v0 * v0 + v1 * v1;
  __syncthreads();
  #pragma unroll
  for (int off = 128; off > 0; off >>= 1) {
    if (tid < off) { rs[tid] += rs[tid + off]; rss[tid] += rss[tid + off]; }
    __syncthreads();
  }
  float mean = rs[0] * (1.0f / Dc);
  float var = rss[0] * (1.0f / Dc) - mean * mean;
  float r = rsqrtf(var + 1e-5f);
  out[(size_t)row * Dc + tid] = (v0 - mean) * r * g[tid] + bt[tid];
  out[(size_t)row * Dc + tid + 256] = (v1 - mean) * r * g[tid + 256] + bt[tid + 256];
}

// ---------------- host ----------------

extern "C" void kernel_launch(void* const* d_in, const int* in_sizes, int n_in,
                              void* d_out, int out_size, void* d_ws, size_t ws_size,
                              hipStream_t stream) {
  const float* x          = (const float*)d_in[0];
  const float* emb_w      = (const float*)d_in[1];
  const float* enc_Wq     = (const float*)d_in[2];
  const float* enc_bq     = (const float*)d_in[3];
  const float* enc_Wk     = (const float*)d_in[4];
  const float* enc_bk     = (const float*)d_in[5];
  const float* enc_Wv     = (const float*)d_in[6];
  const float* enc_bv     = (const float*)d_in[7];
  const float* enc_Wo     = (const float*)d_in[8];
  const float* enc_bo     = (const float*)d_in[9];
  const float* enc_ln_g   = (const float*)d_in[10];
  const float* enc_ln_b   = (const float*)d_in[11];
  const float* dec_Wq     = (const float*)d_in[12];
  const float* dec_bq     = (const float*)d_in[13];
  const float* dec_Wk     = (const float*)d_in[14];
  const float* dec_bk     = (const float*)d_in[15];
  const float* dec_Wv     = (const float*)d_in[16];
  const float* dec_bv     = (const float*)d_in[17];
  const float* dec_Wo     = (const float*)d_in[18];
  const float* dec_bo     = (const float*)d_in[19];
  const float* dconv1_w   = (const float*)d_in[20];
  const float* dconv1_b   = (const float*)d_in[21];
  const float* dconv2_w   = (const float*)d_in[22];
  const float* dconv2_b   = (const float*)d_in[23];
  const float* dln1_g     = (const float*)d_in[24];
  const float* dln1_b     = (const float*)d_in[25];
  const float* dln2_g     = (const float*)d_in[26];
  const float* dln2_b     = (const float*)d_in[27];
  const float* pro_w1     = (const float*)d_in[28];
  const float* pro_b1     = (const float*)d_in[29];
  const float* pro_w2     = (const float*)d_in[30];
  const float* pro_b2     = (const float*)d_in[31];
  const float* mask_token = (const float*)d_in[32];

  float* out = (float*)d_out;
  float* ws  = (float*)d_ws;

  const size_t BLD = (size_t)Bc * Lc * Dc;      // 16 MB slots
  float* slotA = ws;
  float* slotB = ws + BLD;
  float* slotC = ws + 2 * BLD;
  float* slotD = ws + 3 * BLD;
  float* diffb = ws + 4 * BLD;
  int*   mlist = (int*)(diffb + (size_t)Bc * Lc);
  int*   ulist = mlist + Bc * TRc;

  float* att0 = out;
  float* att1 = out + (size_t)67108864;
  float* att2 = out + (size_t)134217728;
  float* rec  = out + (size_t)201326592;
  float* attbufs[3] = {att0, att1, att2};
  float* hid  = rec;   // FFN hidden chunk (2048x2048) fits rec region exactly

  const size_t Z0 = 0;
  const size_t SU   = (size_t)UNc * Dc;         // enc token batch stride
  const size_t SL   = (size_t)Lc * Dc;          // dec token batch stride
  const size_t SattU = (size_t)UNc * UNPc;      // enc att per-bh stride
  const size_t SattD = (size_t)Lc * Lc;         // dec att per-bh stride

  // 1. embedding -> A
  embed_kernel<<<dim3(Lc, Bc), Dc, 0, stream>>>(x, emb_w, slotA);
  // 2. diff + select
  diff_kernel<<<Bc * Lc, 64, 0, stream>>>(slotA, diffb);
  select_kernel<<<Bc, Lc, 0, stream>>>(diffb, mlist, ulist);
  // 3. gather unmasked: A -> B
  gather_kernel<<<dim3(UNc, Bc), Dc, 0, stream>>>(slotA, ulist, slotB);

  // 4. encoder (3 layers over [B, UN, D])
  int Mu = Bc * UNc;  // 4920
  dim3 lgrid_u(4, (Mu + 127) / 128, 1);
  int uT = (UNc + 127) / 128;  // 5
  for (int i = 0; i < Ec; ++i) {
    const float* Wq = enc_Wq + (size_t)i * Dc * Dc;  const float* bq = enc_bq + i * Dc;
    const float* Wk = enc_Wk + (size_t)i * Dc * Dc;  const float* bk = enc_bk + i * Dc;
    const float* Wv = enc_Wv + (size_t)i * Dc * Dc;  const float* bv = enc_bv + i * Dc;
    const float* Wo = enc_Wo + (size_t)i * Dc * Dc;  const float* bo = enc_bo + i * Dc;
    mfma_gemm<128><<<lgrid_u, 256, 0, stream>>>(slotB, Wq, bq, slotC, Mu, Dc, Dc, Dc,
        Dc, Dc, Dc, Z0, Z0, Z0, Z0, Z0, Z0, 0, 0, 1.0f);
    mfma_gemm<128><<<lgrid_u, 256, 0, stream>>>(slotB, Wk, bk, slotD, Mu, Dc, Dc, Dc,
        Dc, Dc, Dc, Z0, Z0, Z0, Z0, Z0, Z0, 0, 0, 1.0f);
    mfma_gemm<128><<<lgrid_u, 256, 0, stream>>>(slotB, Wv, bv, slotA, Mu, Dc, Dc, Dc,
        Dc, Dc, Dc, Z0, Z0, Z0, Z0, Z0, Z0, 0, 0, 1.0f);
    // QK^T: S = 0.125 * Q K^T  (BT=1), per bh
    mfma_gemm<128><<<dim3(uT, uT, Bc * Hc), 256, 0, stream>>>(slotC, slotD, nullptr, att0,
        UNc, UNc, DHc, DHc, Dc, Dc, UNPc,
        SU, (size_t)DHc, SU, (size_t)DHc, 8 * SattU, SattU, 1, 0, 0.125f);
    softmax_kernel<<<dim3(UNc, Bc * Hc), 256, 0, stream>>>(att0, UNc, UNPc);
    // AV: O = P V  (BT=0, N=64), KA=616 (padded col zeroed), KW=615
    mfma_gemm<64><<<dim3(1, uT, Bc * Hc), 256, 0, stream>>>(att0, slotA, nullptr, slotC,
        UNc, DHc, UNPc, UNc, UNPc, Dc, Dc,
        8 * SattU, SattU, SU, (size_t)DHc, SU, (size_t)DHc, 0, 0, 1.0f);
    mfma_gemm<128><<<lgrid_u, 256, 0, stream>>>(slotC, Wo, bo, slotB, Mu, Dc, Dc, Dc,
        Dc, Dc, Dc, Z0, Z0, Z0, Z0, Z0, Z0, 0, 0, 1.0f);
  }
  layernorm_kernel<<<Mu, 256, 0, stream>>>(slotB, nullptr, 1.0f, enc_ln_g, enc_ln_b, slotC);

  // 5. scatter into full-length token buffer -> A
  scatter_unmasked<<<dim3(UNc, Bc), Dc, 0, stream>>>(slotC, ulist, slotA);
  scatter_masked<<<dim3(TRc, Bc), Dc, 0, stream>>>(mask_token, mlist, slotA);

  // 6. decoder (3 layers over [B, L, D]); att written straight to outputs
  int Md = Bc * Lc;  // 8192
  dim3 lgrid_d(4, Md / 128, 1);
  float* din = slotA;
  float* fr0 = slotB;
  float* fr1 = slotC;
  float* fr2 = slotD;
  for (int i = 0; i < Ec; ++i) {
    const float* Wq = dec_Wq + (size_t)i * Dc * Dc;  const float* bq = dec_bq + i * Dc;
    const float* Wk = dec_Wk + (size_t)i * Dc * Dc;  const float* bk = dec_bk + i * Dc;
    const float* Wv = dec_Wv + (size_t)i * Dc * Dc;  const float* bv = dec_bv + i * Dc;
    const float* Wo = dec_Wo + (size_t)i * Dc * Dc;  const float* bo = dec_bo + i * Dc;
    float* q = fr0; float* k = fr1; float* v = fr2;
    mfma_gemm<128><<<lgrid_d, 256, 0, stream>>>(din, Wq, bq, q, Md, Dc, Dc, Dc,
        Dc, Dc, Dc, Z0, Z0, Z0, Z0, Z0, Z0, 0, 0, 1.0f);
    mfma_gemm<128><<<lgrid_d, 256, 0, stream>>>(din, Wk, bk, k, Md, Dc, Dc, Dc,
        Dc, Dc, Dc, Z0, Z0, Z0, Z0, Z0, Z0, 0, 0, 1.0f);
    mfma_gemm<128><<<lgrid_d, 256, 0, stream>>>(din, Wv, bv, v, Md, Dc, Dc, Dc,
        Dc, Dc, Dc, Z0, Z0, Z0, Z0, Z0, Z0, 0, 0, 1.0f);
    mfma_gemm<128><<<dim3(8, 8, Bc * Hc), 256, 0, stream>>>(q, k, nullptr, attbufs[i],
        Lc, Lc, DHc, DHc, Dc, Dc, Lc,
        SL, (size_t)DHc, SL, (size_t)DHc, 8 * SattD, SattD, 1, 0, 0.125f);
    softmax_kernel<<<dim3(Lc, Bc * Hc), 256, 0, stream>>>(attbufs[i], Lc, Lc);
    mfma_gemm<64><<<dim3(1, 8, Bc * Hc), 256, 0, stream>>>(attbufs[i], v, nullptr, q,
        Lc, DHc, Lc, Lc, Lc, Dc, Dc,
        8 * SattD, SattD, SL, (size_t)DHc, SL, (size_t)DHc, 0, 0, 1.0f);
    mfma_gemm<128><<<lgrid_d, 256, 0, stream>>>(q, Wo, bo, k, Md, Dc, Dc, Dc,
        Dc, Dc, Dc, Z0, Z0, Z0, Z0, Z0, Z0, 0, 0, 1.0f);
    float* ndin = k;
    fr0 = din; fr1 = q; fr2 = v;
    din = ndin;
  }

  // 7. dx = 2*dx; ln1 -> fr0
  float* lnA = fr0;
  layernorm_kernel<<<Md, 256, 0, stream>>>(din, nullptr, 2.0f, dln1_g, dln1_b, lnA);

  // 8. FFN chunked (hidden in rec region): y -> fr1
  float* ybuf = fr1;
  for (int c = 0; c < 4; ++c) {
    const float* Ain = lnA + (size_t)c * 2048 * Dc;
    float* yout = ybuf + (size_t)c * 2048 * Dc;
    mfma_gemm<128><<<dim3(DFFc / 128, 16, 1), 256, 0, stream>>>(Ain, dconv1_w, dconv1_b, hid,
        2048, DFFc, Dc, Dc, Dc, DFFc, DFFc, Z0, Z0, Z0, Z0, Z0, Z0, 0, 1, 1.0f);
    mfma_gemm<128><<<dim3(4, 16, 1), 256, 0, stream>>>(hid, dconv2_w, dconv2_b, yout,
        2048, Dc, DFFc, DFFc, DFFc, Dc, Dc, Z0, Z0, Z0, Z0, Z0, Z0, 0, 0, 1.0f);
  }
  // 9. ln2(lnA + y) -> fr2
  float* ln2o = fr2;
  layernorm_kernel<<<Md, 256, 0, stream>>>(lnA, ybuf, 1.0f, dln2_g, dln2_b, ln2o);

  // 10. projection head: sigmoid(gelu(ln2o@w1+b1)@w2+b2) -> rec
  float* g1 = din;
  mfma_gemm<128><<<lgrid_d, 256, 0, stream>>>(ln2o, pro_w1, pro_b1, g1, Md, Dc, Dc, Dc,
      Dc, Dc, Dc, Z0, Z0, Z0, Z0, Z0, Z0, 0, 2, 1.0f);
  mfma_gemm<128><<<lgrid_d, 256, 0, stream>>>(g1, pro_w2, pro_b2, rec, Md, Dc, Dc, Dc,
      Dc, Dc, Dc, Z0, Z0, Z0, Z0, Z0, Z0, 0, 3, 1.0f);
}

// Round 7
// 5602.320 us; speedup vs baseline: 2.7679x; 1.2886x over previous
//
#include <hip/hip_runtime.h>
#include <math.h>

#define Bc   8
#define Lc   1024
#define CINc 38
#define Dc   512
#define Ec   3
#define Hc   8
#define DHc  64
#define DFFc 2048
#define TRc  409
#define UNc  615
#define UNPc 616   // padded row stride for encoder attention scratch (16B-aligned)

typedef __attribute__((ext_vector_type(8))) short bf16x8;
typedef __attribute__((ext_vector_type(4))) short s16x4;
typedef __attribute__((ext_vector_type(4))) float f32x4;

// ---------------- helpers ----------------

__device__ __forceinline__ float apply_act(float v, int act) {
  if (act == 1) return v > 0.f ? v : 0.f;                       // relu
  if (act == 2) {                                               // gelu (tanh approx, jax default)
    float c = 0.7978845608028654f;
    float t = tanhf(c * (v + 0.044715f * v * v * v));
    return 0.5f * v * (1.0f + t);
  }
  if (act == 3) return 1.0f / (1.0f + expf(-v));                // sigmoid
  return v;
}

// split f32 into hi/lo bf16 (truncation; |err| ~ 2^-16 relative)
__device__ __forceinline__ void split2(float x, short& h, short& l) {
  unsigned u = __float_as_uint(x);
  h = (short)(u >> 16);
  float hf = __uint_as_float(u & 0xFFFF0000u);
  l = (short)(__float_as_uint(x - hf) >> 16);
}

// ---------------- weight prep: transpose + split  W[KxN] -> WT_H/WT_L [NxK] bf16 ----------------
// grid (K/32, N/32, batch), block 256
__global__ __launch_bounds__(256) void prep_w(const float* __restrict__ W,
                                              short* __restrict__ WH, short* __restrict__ WL,
                                              int K, int N) {
  size_t mOff = (size_t)blockIdx.z * K * N;
  const float* Wp = W + mOff;
  short* Hp = WH + mOff;
  short* Lp = WL + mOff;
  __shared__ float t[32][33];
  int k0 = blockIdx.x * 32, n0 = blockIdx.y * 32;
  int tx = threadIdx.x & 31, ty = threadIdx.x >> 5;   // 32 x 8
  for (int i = ty; i < 32; i += 8)
    t[i][tx] = Wp[(size_t)(k0 + i) * N + n0 + tx];
  __syncthreads();
  for (int i = ty; i < 32; i += 8) {
    short h, l; split2(t[tx][i], h, l);
    Hp[(size_t)(n0 + i) * K + k0 + tx] = h;
    Lp[(size_t)(n0 + i) * K + k0 + tx] = l;
  }
}

// ---------------- embedding: circular conv3 + PE (tiled: 32 l's per block) ----------------
// grid (Lc/32, Bc), block 512
#define ELT 32
__global__ __launch_bounds__(512) void embed_kernel(const float* __restrict__ x,
                                                    const float* __restrict__ w,
                                                    float* __restrict__ ex) {
  int l0 = blockIdx.x * ELT, b = blockIdx.y, d = threadIdx.x;
  __shared__ float xs[(ELT + 2) * CINc];
  for (int i = threadIdx.x; i < (ELT + 2) * CINc; i += 512) {
    int li = i / CINc, c = i - li * CINc;
    int lsrc = (l0 + li - 1 + Lc) & (Lc - 1);
    xs[i] = x[((size_t)b * Lc + lsrc) * CINc + c];
  }
  __syncthreads();
  float acc[ELT];
  #pragma unroll
  for (int i = 0; i < ELT; ++i) acc[i] = 0.f;
  for (int kc = 0; kc < 3 * CINc; ++kc) {
    float wv = w[(size_t)kc * Dc + d];
    int k = kc / CINc, c = kc - k * CINc;
    const float* xp = xs + k * CINc + c;
    #pragma unroll
    for (int i = 0; i < ELT; ++i) acc[i] += wv * xp[i * CINc];
  }
  int di = d >> 1;
  float div = expf((float)(2 * di) * (-9.210340371976184f / 512.0f));
  bool isCos = d & 1;
  for (int i = 0; i < ELT; ++i) {
    float ang = (float)(l0 + i) * div;
    float pe = isCos ? cosf(ang) : sinf(ang);
    ex[((size_t)b * Lc + l0 + i) * Dc + d] = acc[i] + pe;
  }
}

__device__ __forceinline__ float pe_val(int pos, int d) {
  int i = d >> 1;
  float div = expf((float)(2 * i) * (-9.210340371976184f / 512.0f));
  float ang = (float)pos * div;
  return (d & 1) ? cosf(ang) : sinf(ang);
}

// ---------------- diff: mean_d |ex[l+1]-ex[l]| ----------------
__global__ void diff_kernel(const float* __restrict__ ex, float* __restrict__ diff) {
  int bl = blockIdx.x;
  int l = bl & (Lc - 1);
  int tid = threadIdx.x;
  if (l == Lc - 1) { if (tid == 0) diff[bl] = -1.0f; return; }  // sentinel: score=inf => smallest
  const float* a = ex + (size_t)bl * Dc;
  const float* b = a + Dc;
  float s = 0.f;
  for (int d = tid; d < Dc; d += 64) s += fabsf(b[d] - a[d]);
  #pragma unroll
  for (int off = 32; off > 0; off >>= 1) s += __shfl_down(s, off);
  if (tid == 0) diff[bl] = s * (1.0f / Dc);
}

// ---------------- dual top-k partition by rank ----------------
__global__ void select_kernel(const float* __restrict__ diff, int* __restrict__ mlist,
                              int* __restrict__ ulist) {
  int b = blockIdx.x, l = threadIdx.x;
  __shared__ float ds[Lc];
  __shared__ int flag[Lc];
  ds[l] = diff[(size_t)b * Lc + l];
  __syncthreads();
  float mine = ds[l];
  int rank = 0;
  for (int j = 0; j < Lc; ++j) {
    float o = ds[j];
    rank += (o < mine) || (o == mine && j < l);
  }
  int is_m = (rank < TRc) ? 1 : 0;
  flag[l] = is_m;
  __syncthreads();
  int pre = 0;
  for (int j = 0; j < l; ++j) pre += flag[j];
  if (is_m) mlist[b * TRc + pre] = l;
  else      ulist[b * UNc + (l - pre)] = l;
}

// ---------------- gather / scatter ----------------
__global__ void gather_kernel(const float* __restrict__ ex, const int* __restrict__ ulist,
                              float* __restrict__ u) {
  int i = blockIdx.x, b = blockIdx.y, d = threadIdx.x;
  int l = ulist[b * UNc + i];
  u[((size_t)b * UNc + i) * Dc + d] = ex[((size_t)b * Lc + l) * Dc + d];
}
__global__ void scatter_unmasked(const float* __restrict__ u, const int* __restrict__ ulist,
                                 float* __restrict__ tokens) {
  int i = blockIdx.x, b = blockIdx.y, d = threadIdx.x;
  int l = ulist[b * UNc + i];
  tokens[((size_t)b * Lc + l) * Dc + d] = u[((size_t)b * UNc + i) * Dc + d];
}
__global__ void scatter_masked(const float* __restrict__ mtok, const int* __restrict__ mlist,
                               float* __restrict__ tokens) {
  int i = blockIdx.x, b = blockIdx.y, d = threadIdx.x;
  int l = mlist[b * TRc + i];
  tokens[((size_t)b * Lc + l) * Dc + d] = mtok[d] + pe_val(l, d);
}

// ---------------- MFMA split-bf16 batched GEMM ----------------
// C = act(scale * A @ B + bias).  A: [M x K] f32 (stride lda).
// MODE 0: B = W [K x N] f32 (stride ldw)            (used by AV: V)
// MODE 1: B = Kmat [N x K] f32 (stride ldw), C=A@B^T (used by QK^T)
// MODE 2: B = pre-split bf16 pair WH/WL [N x K] (stride ldw=K) (all weight GEMMs)
// Batch: grid.z = z; per-operand offset = (z>>3)*s?b + (z&7)*s?h.
// Tile: 128 x TN, K-step 32, 4 waves (2x2), per-wave 64 x TN/2 via 16x16x32 MFMA.
// Split-bf16: x = hi + lo; product = hi*hi + lo*hi + hi*lo (3 MFMAs, ~1.5e-5 rel err).
template<int TN, int MODE>
__global__ __launch_bounds__(256) void mfma_gemm(
    const float* __restrict__ Ab, const float* __restrict__ Wb,
    const short* __restrict__ WHb, const short* __restrict__ WLb,
    const float* __restrict__ bias, float* __restrict__ Cb,
    int M, int N, int KA, int KW, int lda, int ldw, int ldc,
    size_t sAb, size_t sAh, size_t sWb, size_t sWh, size_t sCb, size_t sCh,
    int act, float scale)
{
  constexpr int TM = 128, KS = 32, LK = 40;   // LK: padded k-stride (bf16) -> 80B rows, 16B aligned
  constexpr int FN = TN / 32;                 // n-frags per wave
  __shared__ __align__(16) short AsH[TM][LK], AsL[TM][LK];
  __shared__ __align__(16) short WsH[TN][LK], WsL[TN][LK];
  int z = blockIdx.z, zb = z >> 3, zh = z & 7;
  const float* A = Ab + zb * sAb + zh * sAh;
  int tid = threadIdx.x, lane = tid & 63, w = tid >> 6;
  int ln15 = lane & 15, lg = lane >> 4;
  int rowBase = blockIdx.y * TM, colBase = blockIdx.x * TN;
  int wm = (w >> 1) * 64, wn = (w & 1) * (TN / 2);

  f32x4 acc[4][FN];
  #pragma unroll
  for (int i = 0; i < 4; ++i)
    #pragma unroll
    for (int j = 0; j < FN; ++j) acc[i][j] = (f32x4){0.f, 0.f, 0.f, 0.f};

  for (int k0 = 0; k0 < KA; k0 += KS) {
    // ---- stage A tile (TM x KS): f32 -> hi/lo bf16, rows contiguous in k ----
    for (int v = tid; v < TM * 8; v += 256) {
      int r = v >> 3, kq = v & 7;
      int gr = rowBase + r, gk = k0 + kq * 4;
      float4 f = make_float4(0.f, 0.f, 0.f, 0.f);
      if (gr < M && gk < KA) f = *(const float4*)(A + (size_t)gr * lda + gk);
      float fv[4] = {f.x, f.y, f.z, f.w};
      s16x4 hh, ll;
      #pragma unroll
      for (int i = 0; i < 4; ++i) { short h, l; split2(fv[i], h, l); hh[i] = h; ll[i] = l; }
      *(s16x4*)&AsH[r][kq * 4] = hh;
      *(s16x4*)&AsL[r][kq * 4] = ll;
    }
    // ---- stage B tile ----
    if (MODE == 2) {
      const short* WH = WHb + zb * sWb + zh * sWh;
      const short* WL = WLb + zb * sWb + zh * sWh;
      // pre-split bf16 [N x K]: straight 16B copies (N, K tile-exact for weight GEMMs)
      for (int v = tid; v < TN * 4; v += 256) {
        int r = v >> 2, kq = v & 3;
        *(bf16x8*)&WsH[r][kq * 8] = *(const bf16x8*)(WH + (size_t)(colBase + r) * ldw + k0 + kq * 8);
        *(bf16x8*)&WsL[r][kq * 8] = *(const bf16x8*)(WL + (size_t)(colBase + r) * ldw + k0 + kq * 8);
      }
    } else if (MODE == 1) {
      const float* W = Wb + zb * sWb + zh * sWh;
      // B rows are output columns (C = A@B^T): contiguous-k staging with split
      for (int v = tid; v < TN * 8; v += 256) {
        int r = v >> 3, kq = v & 7;
        int gr = colBase + r, gk = k0 + kq * 4;
        float4 f = make_float4(0.f, 0.f, 0.f, 0.f);
        if (gr < N && gk < KA) f = *(const float4*)(W + (size_t)gr * ldw + gk);
        float fv[4] = {f.x, f.y, f.z, f.w};
        s16x4 hh, ll;
        #pragma unroll
        for (int i = 0; i < 4; ++i) { short h, l; split2(fv[i], h, l); hh[i] = h; ll[i] = l; }
        *(s16x4*)&WsH[r][kq * 4] = hh;
        *(s16x4*)&WsL[r][kq * 4] = ll;
      }
    } else {
      const float* W = Wb + zb * sWb + zh * sWh;
      // W [K x N] f32 row-major -> transposed LDS Wt[n][k]
      constexpr int NQ = TN / 4;
      for (int v = tid; v < KS * NQ; v += 256) {
        int k = v / NQ, n4 = v % NQ;
        int gk = k0 + k;
        float4 f = make_float4(0.f, 0.f, 0.f, 0.f);
        if (gk < KW) f = *(const float4*)(W + (size_t)gk * ldw + colBase + n4 * 4);
        float fv[4] = {f.x, f.y, f.z, f.w};
        #pragma unroll
        for (int i = 0; i < 4; ++i) {
          short h, l; split2(fv[i], h, l);
          WsH[n4 * 4 + i][k] = h;
          WsL[n4 * 4 + i][k] = l;
        }
      }
    }
    __syncthreads();
    // ---- MFMA: per-wave 4 x FN fragments, 3 MFMAs each (split-bf16) ----
    bf16x8 aH[4], aL[4];
    #pragma unroll
    for (int mi = 0; mi < 4; ++mi) {
      aH[mi] = *(const bf16x8*)&AsH[wm + mi * 16 + ln15][lg * 8];
      aL[mi] = *(const bf16x8*)&AsL[wm + mi * 16 + ln15][lg * 8];
    }
    #pragma unroll
    for (int nj = 0; nj < FN; ++nj) {
      bf16x8 bH = *(const bf16x8*)&WsH[wn + nj * 16 + ln15][lg * 8];
      bf16x8 bL = *(const bf16x8*)&WsL[wn + nj * 16 + ln15][lg * 8];
      #pragma unroll
      for (int mi = 0; mi < 4; ++mi) {
        acc[mi][nj] = __builtin_amdgcn_mfma_f32_16x16x32_bf16(aH[mi], bH, acc[mi][nj], 0, 0, 0);
        acc[mi][nj] = __builtin_amdgcn_mfma_f32_16x16x32_bf16(aL[mi], bH, acc[mi][nj], 0, 0, 0);
        acc[mi][nj] = __builtin_amdgcn_mfma_f32_16x16x32_bf16(aH[mi], bL, acc[mi][nj], 0, 0, 0);
      }
    }
    __syncthreads();
  }
  float* C = Cb + zb * sCb + zh * sCh;
  // ---- epilogue: C/D layout col=lane&15, row=(lane>>4)*4+reg (HW-verified) ----
  #pragma unroll
  for (int mi = 0; mi < 4; ++mi) {
    #pragma unroll
    for (int nj = 0; nj < FN; ++nj) {
      int col = colBase + wn + nj * 16 + ln15;
      if (col >= N) continue;
      int row0 = rowBase + wm + mi * 16 + lg * 4;
      float bv = bias ? bias[col] : 0.f;
      #pragma unroll
      for (int rr = 0; rr < 4; ++rr) {
        int row = row0 + rr;
        if (row < M)
          C[(size_t)row * ldc + col] = apply_act(acc[mi][nj][rr] * scale + bv, act);
      }
    }
  }
}

// ---------------- row softmax (in place); zeroes padding tail ----------------
// grid (Lq, B*H), block 256
__global__ __launch_bounds__(256) void softmax_kernel(float* __restrict__ att, int Lq, int Lsr) {
  int q = blockIdx.x, bh = blockIdx.y;
  int tid = threadIdx.x;
  __shared__ float s[Lc];
  __shared__ float red[256];
  float* arow = att + ((size_t)bh * Lq + q) * Lsr;
  float lm = -INFINITY;
  for (int k = tid; k < Lq; k += 256) { float v = arow[k]; s[k] = v; lm = fmaxf(lm, v); }
  red[tid] = lm; __syncthreads();
  #pragma unroll
  for (int off = 128; off > 0; off >>= 1) {
    if (tid < off) red[tid] = fmaxf(red[tid], red[tid + off]);
    __syncthreads();
  }
  float m = red[0]; __syncthreads();
  float ls = 0.f;
  for (int k = tid; k < Lq; k += 256) { float e = expf(s[k] - m); s[k] = e; ls += e; }
  red[tid] = ls; __syncthreads();
  #pragma unroll
  for (int off = 128; off > 0; off >>= 1) {
    if (tid < off) red[tid] += red[tid + off];
    __syncthreads();
  }
  float inv = 1.0f / red[0];
  for (int k = tid; k < Lq; k += 256) arow[k] = s[k] * inv;
  for (int k = Lq + tid; k < Lsr; k += 256) arow[k] = 0.f;   // zero pad for AV k-reads
}

// ---------------- layernorm: out = LN(alpha*x + res) * g + b ----------------
__global__ __launch_bounds__(256) void layernorm_kernel(const float* __restrict__ x,
                                                        const float* __restrict__ res,
                                                        float alpha,
                                                        const float* __restrict__ g,
                                                        const float* __restrict__ bt,
                                                        float* __restrict__ out) {
  int row = blockIdx.x, tid = threadIdx.x;
  const float* xr = x + (size_t)row * Dc;
  float v0 = alpha * xr[tid];
  float v1 = alpha * xr[tid + 256];
  if (res) {
    v0 += res[(size_t)row * Dc + tid];
    v1 += res[(size_t)row * Dc + tid + 256];
  }
  __shared__ float rs[256], rss[256];
  rs[tid] = v0 + v1;
  rss[tid] = v0 * v0 + v1 * v1;
  __syncthreads();
  #pragma unroll
  for (int off = 128; off > 0; off >>= 1) {
    if (tid < off) { rs[tid] += rs[tid + off]; rss[tid] += rss[tid + off]; }
    __syncthreads();
  }
  float mean = rs[0] * (1.0f / Dc);
  float var = rss[0] * (1.0f / Dc) - mean * mean;
  float r = rsqrtf(var + 1e-5f);
  out[(size_t)row * Dc + tid] = (v0 - mean) * r * g[tid] + bt[tid];
  out[(size_t)row * Dc + tid + 256] = (v1 - mean) * r * g[tid + 256] + bt[tid + 256];
}

// ---------------- host ----------------

extern "C" void kernel_launch(void* const* d_in, const int* in_sizes, int n_in,
                              void* d_out, int out_size, void* d_ws, size_t ws_size,
                              hipStream_t stream) {
  const float* x          = (const float*)d_in[0];
  const float* emb_w      = (const float*)d_in[1];
  const float* enc_Wq     = (const float*)d_in[2];
  const float* enc_bq     = (const float*)d_in[3];
  const float* enc_Wk     = (const float*)d_in[4];
  const float* enc_bk     = (const float*)d_in[5];
  const float* enc_Wv     = (const float*)d_in[6];
  const float* enc_bv     = (const float*)d_in[7];
  const float* enc_Wo     = (const float*)d_in[8];
  const float* enc_bo     = (const float*)d_in[9];
  const float* enc_ln_g   = (const float*)d_in[10];
  const float* enc_ln_b   = (const float*)d_in[11];
  const float* dec_Wq     = (const float*)d_in[12];
  const float* dec_bq     = (const float*)d_in[13];
  const float* dec_Wk     = (const float*)d_in[14];
  const float* dec_bk     = (const float*)d_in[15];
  const float* dec_Wv     = (const float*)d_in[16];
  const float* dec_bv     = (const float*)d_in[17];
  const float* dec_Wo     = (const float*)d_in[18];
  const float* dec_bo     = (const float*)d_in[19];
  const float* dconv1_w   = (const float*)d_in[20];
  const float* dconv1_b   = (const float*)d_in[21];
  const float* dconv2_w   = (const float*)d_in[22];
  const float* dconv2_b   = (const float*)d_in[23];
  const float* dln1_g     = (const float*)d_in[24];
  const float* dln1_b     = (const float*)d_in[25];
  const float* dln2_g     = (const float*)d_in[26];
  const float* dln2_b     = (const float*)d_in[27];
  const float* pro_w1     = (const float*)d_in[28];
  const float* pro_b1     = (const float*)d_in[29];
  const float* pro_w2     = (const float*)d_in[30];
  const float* pro_b2     = (const float*)d_in[31];
  const float* mask_token = (const float*)d_in[32];

  float* out = (float*)d_out;
  float* ws  = (float*)d_ws;

  const size_t BLD = (size_t)Bc * Lc * Dc;      // 16 MB slots
  float* slotA = ws;
  float* slotB = ws + BLD;
  float* slotC = ws + 2 * BLD;
  float* slotD = ws + 3 * BLD;
  float* diffb = ws + 4 * BLD;
  int*   mlist = (int*)(diffb + (size_t)Bc * Lc);
  int*   ulist = mlist + Bc * TRc;
  // prep area (shorts) right after the lists (mlist+ulist = exactly 8192 ints)
  short* prep  = (short*)(mlist + 8192);
  const size_t M512 = (size_t)3 * Dc * Dc;      // 786432 (per 3-layer matrix)
  size_t po = 0;
  short* encWqH = prep + po; po += M512;  short* encWqL = prep + po; po += M512;
  short* encWkH = prep + po; po += M512;  short* encWkL = prep + po; po += M512;
  short* encWvH = prep + po; po += M512;  short* encWvL = prep + po; po += M512;
  short* encWoH = prep + po; po += M512;  short* encWoL = prep + po; po += M512;
  short* decWqH = prep + po; po += M512;  short* decWqL = prep + po; po += M512;
  short* decWkH = prep + po; po += M512;  short* decWkL = prep + po; po += M512;
  short* decWvH = prep + po; po += M512;  short* decWvL = prep + po; po += M512;
  short* decWoH = prep + po; po += M512;  short* decWoL = prep + po; po += M512;
  const size_t MFF = (size_t)Dc * DFFc;         // 1048576
  short* conv1H = prep + po; po += MFF;   short* conv1L = prep + po; po += MFF;
  short* conv2H = prep + po; po += MFF;   short* conv2L = prep + po; po += MFF;
  const size_t MPP = (size_t)Dc * Dc;
  short* w1H = prep + po; po += MPP;      short* w1L = prep + po; po += MPP;
  short* w2H = prep + po; po += MPP;      short* w2L = prep + po; po += MPP;

  float* att0 = out;
  float* att1 = out + (size_t)67108864;
  float* att2 = out + (size_t)134217728;
  float* rec  = out + (size_t)201326592;
  float* attbufs[3] = {att0, att1, att2};
  float* hid  = rec;   // FFN hidden chunk (2048x2048) fits rec region exactly

  const size_t Z0 = 0;
  const size_t SU   = (size_t)UNc * Dc;         // enc token batch stride
  const size_t SL   = (size_t)Lc * Dc;          // dec token batch stride
  const size_t SattU = (size_t)UNc * UNPc;      // enc att per-bh stride
  const size_t SattD = (size_t)Lc * Lc;         // dec att per-bh stride

  // 0. weight prep (transpose + split, once per launch)
  prep_w<<<dim3(16, 16, 3), 256, 0, stream>>>(enc_Wq, encWqH, encWqL, Dc, Dc);
  prep_w<<<dim3(16, 16, 3), 256, 0, stream>>>(enc_Wk, encWkH, encWkL, Dc, Dc);
  prep_w<<<dim3(16, 16, 3), 256, 0, stream>>>(enc_Wv, encWvH, encWvL, Dc, Dc);
  prep_w<<<dim3(16, 16, 3), 256, 0, stream>>>(enc_Wo, encWoH, encWoL, Dc, Dc);
  prep_w<<<dim3(16, 16, 3), 256, 0, stream>>>(dec_Wq, decWqH, decWqL, Dc, Dc);
  prep_w<<<dim3(16, 16, 3), 256, 0, stream>>>(dec_Wk, decWkH, decWkL, Dc, Dc);
  prep_w<<<dim3(16, 16, 3), 256, 0, stream>>>(dec_Wv, decWvH, decWvL, Dc, Dc);
  prep_w<<<dim3(16, 16, 3), 256, 0, stream>>>(dec_Wo, decWoH, decWoL, Dc, Dc);
  prep_w<<<dim3(16, 64, 1), 256, 0, stream>>>(dconv1_w, conv1H, conv1L, Dc, DFFc);
  prep_w<<<dim3(64, 16, 1), 256, 0, stream>>>(dconv2_w, conv2H, conv2L, DFFc, Dc);
  prep_w<<<dim3(16, 16, 1), 256, 0, stream>>>(pro_w1, w1H, w1L, Dc, Dc);
  prep_w<<<dim3(16, 16, 1), 256, 0, stream>>>(pro_w2, w2H, w2L, Dc, Dc);

  // 1. embedding -> A
  embed_kernel<<<dim3(Lc / ELT, Bc), 512, 0, stream>>>(x, emb_w, slotA);
  // 2. diff + select
  diff_kernel<<<Bc * Lc, 64, 0, stream>>>(slotA, diffb);
  select_kernel<<<Bc, Lc, 0, stream>>>(diffb, mlist, ulist);
  // 3. gather unmasked: A -> B
  gather_kernel<<<dim3(UNc, Bc), Dc, 0, stream>>>(slotA, ulist, slotB);

  // 4. encoder (3 layers over [B, UN, D])
  int Mu = Bc * UNc;  // 4920
  dim3 lgrid_u(4, (Mu + 127) / 128, 1);
  int uT = (UNc + 127) / 128;  // 5
  for (int i = 0; i < Ec; ++i) {
    size_t wo = (size_t)i * Dc * Dc;
    const float* bq = enc_bq + i * Dc;  const float* bk = enc_bk + i * Dc;
    const float* bv = enc_bv + i * Dc;  const float* bo = enc_bo + i * Dc;
    mfma_gemm<128,2><<<lgrid_u, 256, 0, stream>>>(slotB, nullptr, encWqH + wo, encWqL + wo,
        bq, slotC, Mu, Dc, Dc, Dc, Dc, Dc, Dc, Z0, Z0, Z0, Z0, Z0, Z0, 0, 1.0f);
    mfma_gemm<128,2><<<lgrid_u, 256, 0, stream>>>(slotB, nullptr, encWkH + wo, encWkL + wo,
        bk, slotD, Mu, Dc, Dc, Dc, Dc, Dc, Dc, Z0, Z0, Z0, Z0, Z0, Z0, 0, 1.0f);
    mfma_gemm<128,2><<<lgrid_u, 256, 0, stream>>>(slotB, nullptr, encWvH + wo, encWvL + wo,
        bv, slotA, Mu, Dc, Dc, Dc, Dc, Dc, Dc, Z0, Z0, Z0, Z0, Z0, Z0, 0, 1.0f);
    // QK^T: S = 0.125 * Q K^T (MODE 1), per bh
    mfma_gemm<128,1><<<dim3(uT, uT, Bc * Hc), 256, 0, stream>>>(slotC, slotD, nullptr, nullptr,
        nullptr, att0, UNc, UNc, DHc, DHc, Dc, Dc, UNPc,
        SU, (size_t)DHc, SU, (size_t)DHc, 8 * SattU, SattU, 0, 0.125f);
    softmax_kernel<<<dim3(UNc, Bc * Hc), 256, 0, stream>>>(att0, UNc, UNPc);
    // AV: O = P V  (MODE 0, N=64), KA=616 (padded col zeroed), KW=615
    mfma_gemm<64,0><<<dim3(1, uT, Bc * Hc), 256, 0, stream>>>(att0, slotA, nullptr, nullptr,
        nullptr, slotC, UNc, DHc, UNPc, UNc, UNPc, Dc, Dc,
        8 * SattU, SattU, SU, (size_t)DHc, SU, (size_t)DHc, 0, 1.0f);
    mfma_gemm<128,2><<<lgrid_u, 256, 0, stream>>>(slotC, nullptr, encWoH + wo, encWoL + wo,
        bo, slotB, Mu, Dc, Dc, Dc, Dc, Dc, Dc, Z0, Z0, Z0, Z0, Z0, Z0, 0, 1.0f);
  }
  layernorm_kernel<<<Mu, 256, 0, stream>>>(slotB, nullptr, 1.0f, enc_ln_g, enc_ln_b, slotC);

  // 5. scatter into full-length token buffer -> A
  scatter_unmasked<<<dim3(UNc, Bc), Dc, 0, stream>>>(slotC, ulist, slotA);
  scatter_masked<<<dim3(TRc, Bc), Dc, 0, stream>>>(mask_token, mlist, slotA);

  // 6. decoder (3 layers over [B, L, D]); att written straight to outputs
  int Md = Bc * Lc;  // 8192
  dim3 lgrid_d(4, Md / 128, 1);
  float* din = slotA;
  float* fr0 = slotB;
  float* fr1 = slotC;
  float* fr2 = slotD;
  for (int i = 0; i < Ec; ++i) {
    size_t wo = (size_t)i * Dc * Dc;
    const float* bq = dec_bq + i * Dc;  const float* bk = dec_bk + i * Dc;
    const float* bv = dec_bv + i * Dc;  const float* bo = dec_bo + i * Dc;
    float* q = fr0; float* k = fr1; float* v = fr2;
    mfma_gemm<128,2><<<lgrid_d, 256, 0, stream>>>(din, nullptr, decWqH + wo, decWqL + wo,
        bq, q, Md, Dc, Dc, Dc, Dc, Dc, Dc, Z0, Z0, Z0, Z0, Z0, Z0, 0, 1.0f);
    mfma_gemm<128,2><<<lgrid_d, 256, 0, stream>>>(din, nullptr, decWkH + wo, decWkL + wo,
        bk, k, Md, Dc, Dc, Dc, Dc, Dc, Dc, Z0, Z0, Z0, Z0, Z0, Z0, 0, 1.0f);
    mfma_gemm<128,2><<<lgrid_d, 256, 0, stream>>>(din, nullptr, decWvH + wo, decWvL + wo,
        bv, v, Md, Dc, Dc, Dc, Dc, Dc, Dc, Z0, Z0, Z0, Z0, Z0, Z0, 0, 1.0f);
    mfma_gemm<128,1><<<dim3(8, 8, Bc * Hc), 256, 0, stream>>>(q, k, nullptr, nullptr,
        nullptr, attbufs[i], Lc, Lc, DHc, DHc, Dc, Dc, Lc,
        SL, (size_t)DHc, SL, (size_t)DHc, 8 * SattD, SattD, 0, 0.125f);
    softmax_kernel<<<dim3(Lc, Bc * Hc), 256, 0, stream>>>(attbufs[i], Lc, Lc);
    mfma_gemm<64,0><<<dim3(1, 8, Bc * Hc), 256, 0, stream>>>(attbufs[i], v, nullptr, nullptr,
        nullptr, q, Lc, DHc, Lc, Lc, Lc, Dc, Dc,
        8 * SattD, SattD, SL, (size_t)DHc, SL, (size_t)DHc, 0, 1.0f);
    mfma_gemm<128,2><<<lgrid_d, 256, 0, stream>>>(q, nullptr, decWoH + wo, decWoL + wo,
        bo, k, Md, Dc, Dc, Dc, Dc, Dc, Dc, Z0, Z0, Z0, Z0, Z0, Z0, 0, 1.0f);
    float* ndin = k;
    fr0 = din; fr1 = q; fr2 = v;
    din = ndin;
  }

  // 7. dx = 2*dx; ln1 -> fr0
  float* lnA = fr0;
  layernorm_kernel<<<Md, 256, 0, stream>>>(din, nullptr, 2.0f, dln1_g, dln1_b, lnA);

  // 8. FFN chunked (hidden in rec region): y -> fr1
  float* ybuf = fr1;
  for (int c = 0; c < 4; ++c) {
    const float* Ain = lnA + (size_t)c * 2048 * Dc;
    float* yout = ybuf + (size_t)c * 2048 * Dc;
    mfma_gemm<128,2><<<dim3(DFFc / 128, 16, 1), 256, 0, stream>>>(Ain, nullptr, conv1H, conv1L,
        dconv1_b, hid, 2048, DFFc, Dc, Dc, Dc, Dc, DFFc, Z0, Z0, Z0, Z0, Z0, Z0, 1, 1.0f);
    mfma_gemm<128,2><<<dim3(4, 16, 1), 256, 0, stream>>>(hid, nullptr, conv2H, conv2L,
        dconv2_b, yout, 2048, Dc, DFFc, DFFc, DFFc, DFFc, Dc, Z0, Z0, Z0, Z0, Z0, Z0, 0, 1.0f);
  }
  // 9. ln2(lnA + y) -> fr2
  float* ln2o = fr2;
  layernorm_kernel<<<Md, 256, 0, stream>>>(lnA, ybuf, 1.0f, dln2_g, dln2_b, ln2o);

  // 10. projection head: sigmoid(gelu(ln2o@w1+b1)@w2+b2) -> rec
  float* g1 = din;
  mfma_gemm<128,2><<<lgrid_d, 256, 0, stream>>>(ln2o, nullptr, w1H, w1L, pro_b1, g1,
      Md, Dc, Dc, Dc, Dc, Dc, Dc, Z0, Z0, Z0, Z0, Z0, Z0, 2, 1.0f);
  mfma_gemm<128,2><<<lgrid_d, 256, 0, stream>>>(g1, nullptr, w2H, w2L, pro_b2, rec,
      Md, Dc, Dc, Dc, Dc, Dc, Dc, Z0, Z0, Z0, Z0, Z0, Z0, 3, 1.0f);
}

// Round 8
// 4385.661 us; speedup vs baseline: 3.5357x; 1.2774x over previous
//
#include <hip/hip_runtime.h>
#include <math.h>

#define Bc   8
#define Lc   1024
#define CINc 38
#define Dc   512
#define Ec   3
#define Hc   8
#define DHc  64
#define DFFc 2048
#define TRc  409
#define UNc  615
#define UNPc 616   // padded row stride for encoder attention scratch (16B-aligned)

typedef __attribute__((ext_vector_type(8))) short bf16x8;
typedef __attribute__((ext_vector_type(4))) short s16x4;
typedef __attribute__((ext_vector_type(4))) float f32x4;

// ---------------- helpers ----------------

__device__ __forceinline__ float apply_act(float v, int act) {
  if (act == 1) return v > 0.f ? v : 0.f;                       // relu
  if (act == 2) {                                               // gelu (tanh approx, jax default)
    float c = 0.7978845608028654f;
    float t = tanhf(c * (v + 0.044715f * v * v * v));
    return 0.5f * v * (1.0f + t);
  }
  if (act == 3) return 1.0f / (1.0f + expf(-v));                // sigmoid
  return v;
}

// split f32 into hi/lo bf16 (truncation; |err| ~ 2^-16 relative)
__device__ __forceinline__ void split2(float x, short& h, short& l) {
  unsigned u = __float_as_uint(x);
  h = (short)(u >> 16);
  float hf = __uint_as_float(u & 0xFFFF0000u);
  l = (short)(__float_as_uint(x - hf) >> 16);
}

// ---------------- weight prep: transpose + split  W[KxN] -> WT_H/WT_L [NxK] bf16 ----------------
// grid (K/32, N/32, z), block 256. szIn/szOut: per-z strides.
__global__ __launch_bounds__(256) void prep_w(const float* __restrict__ W,
                                              short* __restrict__ WH, short* __restrict__ WL,
                                              int K, int N, size_t szIn, size_t szOut) {
  const float* Wp = W + blockIdx.z * szIn;
  short* Hp = WH + blockIdx.z * szOut;
  short* Lp = WL + blockIdx.z * szOut;
  __shared__ float t[32][33];
  int k0 = blockIdx.x * 32, n0 = blockIdx.y * 32;
  int tx = threadIdx.x & 31, ty = threadIdx.x >> 5;   // 32 x 8
  for (int i = ty; i < 32; i += 8)
    t[i][tx] = Wp[(size_t)(k0 + i) * N + n0 + tx];
  __syncthreads();
  for (int i = ty; i < 32; i += 8) {
    short h, l; split2(t[tx][i], h, l);
    Hp[(size_t)(n0 + i) * K + k0 + tx] = h;
    Lp[(size_t)(n0 + i) * K + k0 + tx] = l;
  }
}

// concat per-layer q/k/v biases into [E x 1536]
__global__ void concat_bias3(const float* __restrict__ bq, const float* __restrict__ bk,
                             const float* __restrict__ bv, float* __restrict__ o) {
  int e = blockIdx.x, t = threadIdx.x;
  o[e * 1536 + t]        = bq[e * 512 + t];
  o[e * 1536 + 512 + t]  = bk[e * 512 + t];
  o[e * 1536 + 1024 + t] = bv[e * 512 + t];
}

// split activation matrix: in f32 [rows x ldin] (cols [0,ncols)) -> H/L bf16 [rows x ldout]
// grid rows, block 256 (4 f32/thread/iter)
__global__ __launch_bounds__(256) void split_cols(const float* __restrict__ in, int ldin,
                                                  short* __restrict__ H, short* __restrict__ L,
                                                  int ldout, int ncols) {
  int row = blockIdx.x, tid = threadIdx.x;
  const float* ip = in + (size_t)row * ldin;
  short* hp = H + (size_t)row * ldout;
  short* lp = L + (size_t)row * ldout;
  for (int c = tid * 4; c < ncols; c += 1024) {
    float4 f = *(const float4*)(ip + c);
    float fv[4] = {f.x, f.y, f.z, f.w};
    s16x4 hh, ll;
    #pragma unroll
    for (int i = 0; i < 4; ++i) { short h, l; split2(fv[i], h, l); hh[i] = h; ll[i] = l; }
    *(s16x4*)(hp + c) = hh;
    *(s16x4*)(lp + c) = ll;
  }
}

// ---------------- embedding: circular conv3 + PE (tiled: 32 l's per block) ----------------
#define ELT 32
__global__ __launch_bounds__(512) void embed_kernel(const float* __restrict__ x,
                                                    const float* __restrict__ w,
                                                    float* __restrict__ ex) {
  int l0 = blockIdx.x * ELT, b = blockIdx.y, d = threadIdx.x;
  __shared__ float xs[(ELT + 2) * CINc];
  for (int i = threadIdx.x; i < (ELT + 2) * CINc; i += 512) {
    int li = i / CINc, c = i - li * CINc;
    int lsrc = (l0 + li - 1 + Lc) & (Lc - 1);
    xs[i] = x[((size_t)b * Lc + lsrc) * CINc + c];
  }
  __syncthreads();
  float acc[ELT];
  #pragma unroll
  for (int i = 0; i < ELT; ++i) acc[i] = 0.f;
  for (int kc = 0; kc < 3 * CINc; ++kc) {
    float wv = w[(size_t)kc * Dc + d];
    int k = kc / CINc, c = kc - k * CINc;
    const float* xp = xs + k * CINc + c;
    #pragma unroll
    for (int i = 0; i < ELT; ++i) acc[i] += wv * xp[i * CINc];
  }
  int di = d >> 1;
  float div = expf((float)(2 * di) * (-9.210340371976184f / 512.0f));
  bool isCos = d & 1;
  for (int i = 0; i < ELT; ++i) {
    float ang = (float)(l0 + i) * div;
    float pe = isCos ? cosf(ang) : sinf(ang);
    ex[((size_t)b * Lc + l0 + i) * Dc + d] = acc[i] + pe;
  }
}

__device__ __forceinline__ float pe_val(int pos, int d) {
  int i = d >> 1;
  float div = expf((float)(2 * i) * (-9.210340371976184f / 512.0f));
  float ang = (float)pos * div;
  return (d & 1) ? cosf(ang) : sinf(ang);
}

// ---------------- diff / select / gather / scatter ----------------
__global__ void diff_kernel(const float* __restrict__ ex, float* __restrict__ diff) {
  int bl = blockIdx.x;
  int l = bl & (Lc - 1);
  int tid = threadIdx.x;
  if (l == Lc - 1) { if (tid == 0) diff[bl] = -1.0f; return; }  // sentinel: score=inf => smallest
  const float* a = ex + (size_t)bl * Dc;
  const float* b = a + Dc;
  float s = 0.f;
  for (int d = tid; d < Dc; d += 64) s += fabsf(b[d] - a[d]);
  #pragma unroll
  for (int off = 32; off > 0; off >>= 1) s += __shfl_down(s, off);
  if (tid == 0) diff[bl] = s * (1.0f / Dc);
}

__global__ void select_kernel(const float* __restrict__ diff, int* __restrict__ mlist,
                              int* __restrict__ ulist) {
  int b = blockIdx.x, l = threadIdx.x;
  __shared__ float ds[Lc];
  __shared__ int flag[Lc];
  ds[l] = diff[(size_t)b * Lc + l];
  __syncthreads();
  float mine = ds[l];
  int rank = 0;
  for (int j = 0; j < Lc; ++j) {
    float o = ds[j];
    rank += (o < mine) || (o == mine && j < l);
  }
  int is_m = (rank < TRc) ? 1 : 0;
  flag[l] = is_m;
  __syncthreads();
  int pre = 0;
  for (int j = 0; j < l; ++j) pre += flag[j];
  if (is_m) mlist[b * TRc + pre] = l;
  else      ulist[b * UNc + (l - pre)] = l;
}

__global__ void gather_kernel(const float* __restrict__ ex, const int* __restrict__ ulist,
                              float* __restrict__ u) {
  int i = blockIdx.x, b = blockIdx.y, d = threadIdx.x;
  int l = ulist[b * UNc + i];
  u[((size_t)b * UNc + i) * Dc + d] = ex[((size_t)b * Lc + l) * Dc + d];
}
__global__ void scatter_unmasked(const float* __restrict__ u, const int* __restrict__ ulist,
                                 float* __restrict__ tokens) {
  int i = blockIdx.x, b = blockIdx.y, d = threadIdx.x;
  int l = ulist[b * UNc + i];
  tokens[((size_t)b * Lc + l) * Dc + d] = u[((size_t)b * UNc + i) * Dc + d];
}
__global__ void scatter_masked(const float* __restrict__ mtok, const int* __restrict__ mlist,
                               float* __restrict__ tokens) {
  int i = blockIdx.x, b = blockIdx.y, d = threadIdx.x;
  int l = mlist[b * TRc + i];
  tokens[((size_t)b * Lc + l) * Dc + d] = mtok[d] + pe_val(l, d);
}

// ---------------- MFMA split-bf16 batched GEMM ----------------
// C = act(scale * A @ B + bias).
// AMODE 0: A f32 [M x lda] (split in kernel)    AMODE 1: AH/AL bf16 [M x lda] pre-split
// WMODE 0: W f32 [K x N] (transpose+split)      WMODE 2: WH/WL bf16 [N x K] pre-split
// Batch: z = blockIdx.z; per-operand offset = (z>>3)*s?b + (z&7)*s?h.
// Tile 128 x TN, K-step 32, 4 waves (2x2). Split-bf16: hi*hi + lo*hi + hi*lo.
template<int TN, int AMODE, int WMODE>
__global__ __launch_bounds__(256) void mfma_gemm(
    const float* __restrict__ Af, const short* __restrict__ AHb, const short* __restrict__ ALb,
    const float* __restrict__ Wf, const short* __restrict__ WHb, const short* __restrict__ WLb,
    const float* __restrict__ bias, float* __restrict__ Cb,
    int M, int N, int KA, int KW, int lda, int ldw, int ldc,
    size_t sAb, size_t sAh, size_t sWb, size_t sWh, size_t sCb, size_t sCh,
    int act, float scale)
{
  constexpr int TM = 128, KS = 32, LK = 40;
  constexpr int FN = TN / 32;
  __shared__ __align__(16) short AsH[TM][LK], AsL[TM][LK];
  __shared__ __align__(16) short WsH[TN][LK], WsL[TN][LK];
  int z = blockIdx.z, zb = z >> 3, zh = z & 7;
  int tid = threadIdx.x, lane = tid & 63, w = tid >> 6;
  int ln15 = lane & 15, lg = lane >> 4;
  int rowBase = blockIdx.y * TM, colBase = blockIdx.x * TN;
  int wm = (w >> 1) * 64, wn = (w & 1) * (TN / 2);

  f32x4 acc[4][FN];
  #pragma unroll
  for (int i = 0; i < 4; ++i)
    #pragma unroll
    for (int j = 0; j < FN; ++j) acc[i][j] = (f32x4){0.f, 0.f, 0.f, 0.f};

  for (int k0 = 0; k0 < KA; k0 += KS) {
    // ---- stage A tile ----
    if constexpr (AMODE == 1) {
      const short* AH = AHb + zb * sAb + zh * sAh;
      const short* AL = ALb + zb * sAb + zh * sAh;
      for (int v = tid; v < TM * 4; v += 256) {
        int r = v >> 2, kq = v & 3;
        int gr = rowBase + r;
        bf16x8 h = {}, l = {};
        if (gr < M) {
          h = *(const bf16x8*)(AH + (size_t)gr * lda + k0 + kq * 8);
          l = *(const bf16x8*)(AL + (size_t)gr * lda + k0 + kq * 8);
        }
        *(bf16x8*)&AsH[r][kq * 8] = h;
        *(bf16x8*)&AsL[r][kq * 8] = l;
      }
    } else {
      const float* A = Af + zb * sAb + zh * sAh;
      for (int v = tid; v < TM * 8; v += 256) {
        int r = v >> 3, kq = v & 7;
        int gr = rowBase + r, gk = k0 + kq * 4;
        float4 f = make_float4(0.f, 0.f, 0.f, 0.f);
        if (gr < M && gk < KA) f = *(const float4*)(A + (size_t)gr * lda + gk);
        float fv[4] = {f.x, f.y, f.z, f.w};
        s16x4 hh, ll;
        #pragma unroll
        for (int i = 0; i < 4; ++i) { short h, l; split2(fv[i], h, l); hh[i] = h; ll[i] = l; }
        *(s16x4*)&AsH[r][kq * 4] = hh;
        *(s16x4*)&AsL[r][kq * 4] = ll;
      }
    }
    // ---- stage W tile ----
    if constexpr (WMODE == 2) {
      const short* WH = WHb + zb * sWb + zh * sWh;
      const short* WL = WLb + zb * sWb + zh * sWh;
      for (int v = tid; v < TN * 4; v += 256) {
        int r = v >> 2, kq = v & 3;
        int gr = colBase + r;
        bf16x8 h = {}, l = {};
        if (gr < N) {
          h = *(const bf16x8*)(WH + (size_t)gr * ldw + k0 + kq * 8);
          l = *(const bf16x8*)(WL + (size_t)gr * ldw + k0 + kq * 8);
        }
        *(bf16x8*)&WsH[r][kq * 8] = h;
        *(bf16x8*)&WsL[r][kq * 8] = l;
      }
    } else {
      const float* W = Wf + zb * sWb + zh * sWh;
      // W [K x N] f32 row-major -> transposed LDS Wt[n][k] with split
      constexpr int NQ = TN / 4;
      for (int v = tid; v < KS * NQ; v += 256) {
        int k = v / NQ, n4 = v % NQ;
        int gk = k0 + k;
        float4 f = make_float4(0.f, 0.f, 0.f, 0.f);
        if (gk < KW) f = *(const float4*)(W + (size_t)gk * ldw + colBase + n4 * 4);
        float fv[4] = {f.x, f.y, f.z, f.w};
        #pragma unroll
        for (int i = 0; i < 4; ++i) {
          short h, l; split2(fv[i], h, l);
          WsH[n4 * 4 + i][k] = h;
          WsL[n4 * 4 + i][k] = l;
        }
      }
    }
    __syncthreads();
    // ---- MFMA ----
    bf16x8 aH[4], aL[4];
    #pragma unroll
    for (int mi = 0; mi < 4; ++mi) {
      aH[mi] = *(const bf16x8*)&AsH[wm + mi * 16 + ln15][lg * 8];
      aL[mi] = *(const bf16x8*)&AsL[wm + mi * 16 + ln15][lg * 8];
    }
    #pragma unroll
    for (int nj = 0; nj < FN; ++nj) {
      bf16x8 bH = *(const bf16x8*)&WsH[wn + nj * 16 + ln15][lg * 8];
      bf16x8 bL = *(const bf16x8*)&WsL[wn + nj * 16 + ln15][lg * 8];
      #pragma unroll
      for (int mi = 0; mi < 4; ++mi) {
        acc[mi][nj] = __builtin_amdgcn_mfma_f32_16x16x32_bf16(aH[mi], bH, acc[mi][nj], 0, 0, 0);
        acc[mi][nj] = __builtin_amdgcn_mfma_f32_16x16x32_bf16(aL[mi], bH, acc[mi][nj], 0, 0, 0);
        acc[mi][nj] = __builtin_amdgcn_mfma_f32_16x16x32_bf16(aH[mi], bL, acc[mi][nj], 0, 0, 0);
      }
    }
    __syncthreads();
  }
  float* C = Cb + zb * sCb + zh * sCh;
  // epilogue: C/D layout col=lane&15, row=(lane>>4)*4+reg (HW-verified)
  #pragma unroll
  for (int mi = 0; mi < 4; ++mi) {
    #pragma unroll
    for (int nj = 0; nj < FN; ++nj) {
      int col = colBase + wn + nj * 16 + ln15;
      if (col >= N) continue;
      int row0 = rowBase + wm + mi * 16 + lg * 4;
      float bv = bias ? bias[col] : 0.f;
      #pragma unroll
      for (int rr = 0; rr < 4; ++rr) {
        int row = row0 + rr;
        if (row < M)
          C[(size_t)row * ldc + col] = apply_act(acc[mi][nj][rr] * scale + bv, act);
      }
    }
  }
}

// ---------------- row softmax (in place); zeroes padding tail ----------------
__global__ __launch_bounds__(256) void softmax_kernel(float* __restrict__ att, int Lq, int Lsr) {
  int q = blockIdx.x, bh = blockIdx.y;
  int tid = threadIdx.x;
  __shared__ float s[Lc];
  __shared__ float red[256];
  float* arow = att + ((size_t)bh * Lq + q) * Lsr;
  float lm = -INFINITY;
  for (int k = tid; k < Lq; k += 256) { float v = arow[k]; s[k] = v; lm = fmaxf(lm, v); }
  red[tid] = lm; __syncthreads();
  #pragma unroll
  for (int off = 128; off > 0; off >>= 1) {
    if (tid < off) red[tid] = fmaxf(red[tid], red[tid + off]);
    __syncthreads();
  }
  float m = red[0]; __syncthreads();
  float ls = 0.f;
  for (int k = tid; k < Lq; k += 256) { float e = expf(s[k] - m); s[k] = e; ls += e; }
  red[tid] = ls; __syncthreads();
  #pragma unroll
  for (int off = 128; off > 0; off >>= 1) {
    if (tid < off) red[tid] += red[tid + off];
    __syncthreads();
  }
  float inv = 1.0f / red[0];
  for (int k = tid; k < Lq; k += 256) arow[k] = s[k] * inv;
  for (int k = Lq + tid; k < Lsr; k += 256) arow[k] = 0.f;
}

// ---------------- layernorm ----------------
__global__ __launch_bounds__(256) void layernorm_kernel(const float* __restrict__ x,
                                                        const float* __restrict__ res,
                                                        float alpha,
                                                        const float* __restrict__ g,
                                                        const float* __restrict__ bt,
                                                        float* __restrict__ out) {
  int row = blockIdx.x, tid = threadIdx.x;
  const float* xr = x + (size_t)row * Dc;
  float v0 = alpha * xr[tid];
  float v1 = alpha * xr[tid + 256];
  if (res) {
    v0 += res[(size_t)row * Dc + tid];
    v1 += res[(size_t)row * Dc + tid + 256];
  }
  __shared__ float rs[256], rss[256];
  rs[tid] = v0 + v1;
  rss[tid] = v0 * v0 + v1 * v1;
  __syncthreads();
  #pragma unroll
  for (int off = 128; off > 0; off >>= 1) {
    if (tid < off) { rs[tid] += rs[tid + off]; rss[tid] += rss[tid + off]; }
    __syncthreads();
  }
  float mean = rs[0] * (1.0f / Dc);
  float var = rss[0] * (1.0f / Dc) - mean * mean;
  float r = rsqrtf(var + 1e-5f);
  out[(size_t)row * Dc + tid] = (v0 - mean) * r * g[tid] + bt[tid];
  out[(size_t)row * Dc + tid + 256] = (v1 - mean) * r * g[tid + 256] + bt[tid + 256];
}

// ---------------- host ----------------

extern "C" void kernel_launch(void* const* d_in, const int* in_sizes, int n_in,
                              void* d_out, int out_size, void* d_ws, size_t ws_size,
                              hipStream_t stream) {
  const float* x          = (const float*)d_in[0];
  const float* emb_w      = (const float*)d_in[1];
  const float* enc_Wq     = (const float*)d_in[2];
  const float* enc_bq     = (const float*)d_in[3];
  const float* enc_Wk     = (const float*)d_in[4];
  const float* enc_bk     = (const float*)d_in[5];
  const float* enc_Wv     = (const float*)d_in[6];
  const float* enc_bv     = (const float*)d_in[7];
  const float* enc_Wo     = (const float*)d_in[8];
  const float* enc_bo     = (const float*)d_in[9];
  const float* enc_ln_g   = (const float*)d_in[10];
  const float* enc_ln_b   = (const float*)d_in[11];
  const float* dec_Wq     = (const float*)d_in[12];
  const float* dec_bq     = (const float*)d_in[13];
  const float* dec_Wk     = (const float*)d_in[14];
  const float* dec_bk     = (const float*)d_in[15];
  const float* dec_Wv     = (const float*)d_in[16];
  const float* dec_bv     = (const float*)d_in[17];
  const float* dec_Wo     = (const float*)d_in[18];
  const float* dec_bo     = (const float*)d_in[19];
  const float* dconv1_w   = (const float*)d_in[20];
  const float* dconv1_b   = (const float*)d_in[21];
  const float* dconv2_w   = (const float*)d_in[22];
  const float* dconv2_b   = (const float*)d_in[23];
  const float* dln1_g     = (const float*)d_in[24];
  const float* dln1_b     = (const float*)d_in[25];
  const float* dln2_g     = (const float*)d_in[26];
  const float* dln2_b     = (const float*)d_in[27];
  const float* pro_w1     = (const float*)d_in[28];
  const float* pro_b1     = (const float*)d_in[29];
  const float* pro_w2     = (const float*)d_in[30];
  const float* pro_b2     = (const float*)d_in[31];
  const float* mask_token = (const float*)d_in[32];

  float* out = (float*)d_out;
  float* ws  = (float*)d_ws;

  const size_t BLD  = (size_t)Bc * Lc * Dc;       // 4.19M floats
  const size_t QKVF = (size_t)Bc * Lc * 1536;     // 12.58M floats
  float* slotA  = ws;
  float* slotB  = ws + BLD;
  float* slotC  = ws + 2 * BLD;
  float* slotD  = ws + 3 * BLD;
  float* qkvbuf = ws + 4 * BLD;
  float* diffb  = qkvbuf + QKVF;
  float* bqkvE  = diffb + 8192;                   // [3 x 1536]
  float* bqkvD  = bqkvE + 4608;
  int*   mlist  = (int*)(bqkvD + 4608);
  int*   ulist  = mlist + Bc * TRc;               // mlist+ulist = 8192 ints
  short* sb     = (short*)(mlist + 8192);
  const size_t SQK = (size_t)Bc * Lc * 1024;      // 8.39M shorts
  const size_t SAC = (size_t)Bc * Lc * 512;       // 4.19M shorts
  size_t po = 0;
  short* qkH  = sb + po; po += SQK;  short* qkL  = sb + po; po += SQK;
  short* actH = sb + po; po += SAC;  short* actL = sb + po; po += SAC;
  short* lnH  = sb + po; po += SAC;  short* lnL  = sb + po; po += SAC;
  const size_t SW3q = (size_t)3 * 1536 * 512;     // 2.36M
  short* encQkvH = sb + po; po += SW3q;  short* encQkvL = sb + po; po += SW3q;
  short* decQkvH = sb + po; po += SW3q;  short* decQkvL = sb + po; po += SW3q;
  const size_t SW3 = (size_t)3 * 512 * 512;
  short* encWoH = sb + po; po += SW3;  short* encWoL = sb + po; po += SW3;
  short* decWoH = sb + po; po += SW3;  short* decWoL = sb + po; po += SW3;
  const size_t MFF = (size_t)Dc * DFFc;
  short* conv1H = sb + po; po += MFF;  short* conv1L = sb + po; po += MFF;
  short* conv2H = sb + po; po += MFF;  short* conv2L = sb + po; po += MFF;
  const size_t MPP = (size_t)Dc * Dc;
  short* w1H = sb + po; po += MPP;  short* w1L = sb + po; po += MPP;
  short* w2H = sb + po; po += MPP;  short* w2L = sb + po; po += MPP;

  float* att0 = out;
  float* att1 = out + (size_t)67108864;
  float* att2 = out + (size_t)134217728;
  float* rec  = out + (size_t)201326592;
  float* attbufs[3] = {att0, att1, att2};
  float* hid  = rec;   // FFN hidden chunk (2048x2048 f32) fits rec region exactly

  const size_t Z0 = 0;
  const size_t SattU = (size_t)UNc * UNPc;
  const size_t SattD = (size_t)Lc * Lc;

  // 0. weight prep
  concat_bias3<<<3, 512, 0, stream>>>(enc_bq, enc_bk, enc_bv, bqkvE);
  concat_bias3<<<3, 512, 0, stream>>>(dec_bq, dec_bk, dec_bv, bqkvD);
  const size_t SLICE = (size_t)512 * 512, LAYW = (size_t)1536 * 512;
  prep_w<<<dim3(16, 16, 3), 256, 0, stream>>>(enc_Wq, encQkvH,             encQkvL,             512, 512, SLICE, LAYW);
  prep_w<<<dim3(16, 16, 3), 256, 0, stream>>>(enc_Wk, encQkvH + SLICE,     encQkvL + SLICE,     512, 512, SLICE, LAYW);
  prep_w<<<dim3(16, 16, 3), 256, 0, stream>>>(enc_Wv, encQkvH + 2 * SLICE, encQkvL + 2 * SLICE, 512, 512, SLICE, LAYW);
  prep_w<<<dim3(16, 16, 3), 256, 0, stream>>>(dec_Wq, decQkvH,             decQkvL,             512, 512, SLICE, LAYW);
  prep_w<<<dim3(16, 16, 3), 256, 0, stream>>>(dec_Wk, decQkvH + SLICE,     decQkvL + SLICE,     512, 512, SLICE, LAYW);
  prep_w<<<dim3(16, 16, 3), 256, 0, stream>>>(dec_Wv, decQkvH + 2 * SLICE, decQkvL + 2 * SLICE, 512, 512, SLICE, LAYW);
  prep_w<<<dim3(16, 16, 3), 256, 0, stream>>>(enc_Wo, encWoH, encWoL, 512, 512, SLICE, SLICE);
  prep_w<<<dim3(16, 16, 3), 256, 0, stream>>>(dec_Wo, decWoH, decWoL, 512, 512, SLICE, SLICE);
  prep_w<<<dim3(16, 64, 1), 256, 0, stream>>>(dconv1_w, conv1H, conv1L, 512, 2048, Z0, Z0);
  prep_w<<<dim3(64, 16, 1), 256, 0, stream>>>(dconv2_w, conv2H, conv2L, 2048, 512, Z0, Z0);
  prep_w<<<dim3(16, 16, 1), 256, 0, stream>>>(pro_w1, w1H, w1L, 512, 512, Z0, Z0);
  prep_w<<<dim3(16, 16, 1), 256, 0, stream>>>(pro_w2, w2H, w2L, 512, 512, Z0, Z0);

  // 1-3. embed, diff, select, gather
  embed_kernel<<<dim3(Lc / ELT, Bc), 512, 0, stream>>>(x, emb_w, slotA);
  diff_kernel<<<Bc * Lc, 64, 0, stream>>>(slotA, diffb);
  select_kernel<<<Bc, Lc, 0, stream>>>(diffb, mlist, ulist);
  gather_kernel<<<dim3(UNc, Bc), Dc, 0, stream>>>(slotA, ulist, slotB);

  // 4. encoder
  int Mu = Bc * UNc;  // 4920
  int yU = (Mu + 127) / 128;  // 39
  int uT = (UNc + 127) / 128; // 5
  for (int i = 0; i < Ec; ++i) {
    split_cols<<<Mu, 256, 0, stream>>>(slotB, 512, actH, actL, 512, 512);
    mfma_gemm<128,1,2><<<dim3(12, yU, 1), 256, 0, stream>>>(
        nullptr, actH, actL, nullptr, encQkvH + i * LAYW, encQkvL + i * LAYW,
        bqkvE + i * 1536, qkvbuf, Mu, 1536, 512, 512, 512, 512, 1536,
        Z0, Z0, Z0, Z0, Z0, Z0, 0, 1.0f);
    split_cols<<<Mu, 256, 0, stream>>>(qkvbuf, 1536, qkH, qkL, 1024, 1024);
    mfma_gemm<128,1,2><<<dim3(uT, uT, Bc * Hc), 256, 0, stream>>>(
        nullptr, qkH, qkL, nullptr, qkH + 512, qkL + 512, nullptr, att0,
        UNc, UNc, 64, 64, 1024, 1024, UNPc,
        (size_t)UNc * 1024, 64, (size_t)UNc * 1024, 64, 8 * SattU, SattU, 0, 0.125f);
    softmax_kernel<<<dim3(UNc, Bc * Hc), 256, 0, stream>>>(att0, UNc, UNPc);
    mfma_gemm<64,0,0><<<dim3(1, uT, Bc * Hc), 256, 0, stream>>>(
        att0, nullptr, nullptr, qkvbuf + 1024, nullptr, nullptr, nullptr, slotC,
        UNc, 64, UNPc, UNc, UNPc, 1536, 512,
        8 * SattU, SattU, (size_t)UNc * 1536, 64, (size_t)UNc * 512, 64, 0, 1.0f);
    split_cols<<<Mu, 256, 0, stream>>>(slotC, 512, actH, actL, 512, 512);
    mfma_gemm<128,1,2><<<dim3(4, yU, 1), 256, 0, stream>>>(
        nullptr, actH, actL, nullptr, encWoH + i * SLICE, encWoL + i * SLICE,
        enc_bo + i * 512, slotB, Mu, 512, 512, 512, 512, 512, 512,
        Z0, Z0, Z0, Z0, Z0, Z0, 0, 1.0f);
  }
  layernorm_kernel<<<Mu, 256, 0, stream>>>(slotB, nullptr, 1.0f, enc_ln_g, enc_ln_b, slotC);

  // 5. scatter -> slotA (tokens)
  scatter_unmasked<<<dim3(UNc, Bc), Dc, 0, stream>>>(slotC, ulist, slotA);
  scatter_masked<<<dim3(TRc, Bc), Dc, 0, stream>>>(mask_token, mlist, slotA);

  // 6. decoder; avout fixed in slotD; din rotates A->B->C
  int Md = Bc * Lc;  // 8192
  float* dbufs[3] = {slotA, slotB, slotC};
  for (int i = 0; i < Ec; ++i) {
    float* din  = dbufs[i % 3];
    float* dout = dbufs[(i + 1) % 3];
    split_cols<<<Md, 256, 0, stream>>>(din, 512, actH, actL, 512, 512);
    mfma_gemm<128,1,2><<<dim3(12, 64, 1), 256, 0, stream>>>(
        nullptr, actH, actL, nullptr, decQkvH + i * LAYW, decQkvL + i * LAYW,
        bqkvD + i * 1536, qkvbuf, Md, 1536, 512, 512, 512, 512, 1536,
        Z0, Z0, Z0, Z0, Z0, Z0, 0, 1.0f);
    split_cols<<<Md, 256, 0, stream>>>(qkvbuf, 1536, qkH, qkL, 1024, 1024);
    mfma_gemm<128,1,2><<<dim3(8, 8, Bc * Hc), 256, 0, stream>>>(
        nullptr, qkH, qkL, nullptr, qkH + 512, qkL + 512, nullptr, attbufs[i],
        Lc, Lc, 64, 64, 1024, 1024, Lc,
        (size_t)Lc * 1024, 64, (size_t)Lc * 1024, 64, 8 * SattD, SattD, 0, 0.125f);
    softmax_kernel<<<dim3(Lc, Bc * Hc), 256, 0, stream>>>(attbufs[i], Lc, Lc);
    mfma_gemm<64,0,0><<<dim3(1, 8, Bc * Hc), 256, 0, stream>>>(
        attbufs[i], nullptr, nullptr, qkvbuf + 1024, nullptr, nullptr, nullptr, slotD,
        Lc, 64, Lc, Lc, Lc, 1536, 512,
        8 * SattD, SattD, (size_t)Lc * 1536, 64, (size_t)Lc * 512, 64, 0, 1.0f);
    split_cols<<<Md, 256, 0, stream>>>(slotD, 512, actH, actL, 512, 512);
    mfma_gemm<128,1,2><<<dim3(4, 64, 1), 256, 0, stream>>>(
        nullptr, actH, actL, nullptr, decWoH + i * SLICE, decWoL + i * SLICE,
        dec_bo + i * 512, dout, Md, 512, 512, 512, 512, 512, 512,
        Z0, Z0, Z0, Z0, Z0, Z0, 0, 1.0f);
  }
  float* dxf = dbufs[Ec % 3];            // final decoder output (slotA)
  float* f1  = dbufs[(Ec + 1) % 3];      // free
  float* f2  = dbufs[(Ec + 2) % 3];      // free

  // 7. ln1 (alpha=2) -> f1
  layernorm_kernel<<<Md, 256, 0, stream>>>(dxf, nullptr, 2.0f, dln1_g, dln1_b, f1);

  // 8. FFN (A pre-split once; hidden in rec region, split into actH/L per chunk): y -> f2
  split_cols<<<Md, 256, 0, stream>>>(f1, 512, lnH, lnL, 512, 512);
  for (int c = 0; c < 4; ++c) {
    mfma_gemm<128,1,2><<<dim3(16, 16, 1), 256, 0, stream>>>(
        nullptr, lnH + (size_t)c * 2048 * 512, lnL + (size_t)c * 2048 * 512,
        nullptr, conv1H, conv1L, dconv1_b, hid, 2048, 2048, 512, 512, 512, 512, 2048,
        Z0, Z0, Z0, Z0, Z0, Z0, 1, 1.0f);
    split_cols<<<2048, 256, 0, stream>>>(hid, 2048, actH, actL, 2048, 2048);
    mfma_gemm<128,1,2><<<dim3(4, 16, 1), 256, 0, stream>>>(
        nullptr, actH, actL, nullptr, conv2H, conv2L, dconv2_b,
        f2 + (size_t)c * 2048 * 512, 2048, 512, 2048, 2048, 2048, 2048, 512,
        Z0, Z0, Z0, Z0, Z0, Z0, 0, 1.0f);
  }
  // 9. ln2(f1 + f2) -> dxf
  layernorm_kernel<<<Md, 256, 0, stream>>>(f1, f2, 1.0f, dln2_g, dln2_b, dxf);

  // 10. projection: sigmoid(gelu(dxf@w1+b1)@w2+b2) -> rec
  split_cols<<<Md, 256, 0, stream>>>(dxf, 512, actH, actL, 512, 512);
  mfma_gemm<128,1,2><<<dim3(4, 64, 1), 256, 0, stream>>>(
      nullptr, actH, actL, nullptr, w1H, w1L, pro_b1, f1,
      Md, 512, 512, 512, 512, 512, 512, Z0, Z0, Z0, Z0, Z0, Z0, 2, 1.0f);
  split_cols<<<Md, 256, 0, stream>>>(f1, 512, lnH, lnL, 512, 512);
  mfma_gemm<128,1,2><<<dim3(4, 64, 1), 256, 0, stream>>>(
      nullptr, lnH, lnL, nullptr, w2H, w2L, pro_b2, rec,
      Md, 512, 512, 512, 512, 512, 512, Z0, Z0, Z0, Z0, Z0, Z0, 3, 1.0f);
}